// Round 6
// baseline (410.765 us; speedup 1.0000x reference)
//
#include <hip/hip_runtime.h>
#include <hip/hip_bf16.h>
#include <cstdint>
#include <cstddef>

#define DMODEL 1024
#define NHEADS 16
#define HDIM 64
#define BATCH 4
#define SEQ 2048
#define MROWS (BATCH*SEQ)   // 8192
#define N3 (3*DMODEL)       // 3072
#define BHCNT (BATCH*NHEADS) // 64

typedef __attribute__((ext_vector_type(8))) short short8;
typedef __attribute__((ext_vector_type(4))) short short4v;
typedef __attribute__((ext_vector_type(4))) float f32x4;
typedef __attribute__((ext_vector_type(4))) unsigned int uint4v;

// round-to-nearest-even f32 -> bf16 (data has no NaN)
static __device__ __forceinline__ short f2bf(float f) {
  unsigned int u = __builtin_bit_cast(unsigned int, f);
  return (short)((u + 0x7fffu + ((u >> 16) & 1u)) >> 16);
}

// pack two f32 -> one u32 of 2 bf16 (lo, hi) via gfx950 v_cvt_pk_bf16_f32
static __device__ __forceinline__ unsigned int pack_bf16(float lo, float hi) {
  unsigned int r;
  asm("v_cvt_pk_bf16_f32 %0, %1, %2" : "=v"(r) : "v"(lo), "v"(hi));
  return r;
}

// gfx950 fragment-transform swaps:
// permlane32_swap: a.hi32 <-> b.lo32  =>  a'={a.lo,b.lo}, b'={a.hi,b.hi}
// permlane16_swap: a.g1<->b.g0, a.g3<->b.g2 (16-lane groups)
static __device__ __forceinline__ void permlane32_swap(unsigned int& a, unsigned int& b) {
  asm("v_permlane32_swap_b32 %0, %1" : "+v"(a), "+v"(b));
}
static __device__ __forceinline__ void permlane16_swap(unsigned int& a, unsigned int& b) {
  asm("v_permlane16_swap_b32 %0, %1" : "+v"(a), "+v"(b));
}

static __device__ __forceinline__ float fast_exp2(float x) {
#if __has_builtin(__builtin_amdgcn_exp2f)
  return __builtin_amdgcn_exp2f(x);
#else
  return exp2f(x);
#endif
}

static __device__ __forceinline__ void gload16(const void* g, void* l) {
  __builtin_amdgcn_global_load_lds(
      (const __attribute__((address_space(1))) unsigned int*)g,
      (__attribute__((address_space(3))) unsigned int*)l, 16, 0, 0);
}

__global__ __launch_bounds__(256) void cast_x_kernel(
    const float* __restrict__ in, short* __restrict__ out, int n) {
  int i = (blockIdx.x * 256 + threadIdx.x) * 4;
  if (i + 3 < n) {
    float4 v = *(const float4*)(in + i);
    short4v s;
    s[0] = f2bf(v.x); s[1] = f2bf(v.y); s[2] = f2bf(v.z); s[3] = f2bf(v.w);
    *(short4v*)(out + i) = s;
  }
}

// in [K][N] f32 row-major -> out [N][K] bf16 row-major
__global__ __launch_bounds__(256) void transpose_cast_kernel(
    const float* __restrict__ in, short* __restrict__ out, int K, int N) {
  __shared__ float tile[32][33];
  int n0 = blockIdx.x * 32, k0 = blockIdx.y * 32;
  int tx = threadIdx.x, ty = threadIdx.y;  // 32 x 8
#pragma unroll
  for (int i = 0; i < 4; ++i)
    tile[ty + i * 8][tx] = in[(size_t)(k0 + ty + i * 8) * N + (n0 + tx)];
  __syncthreads();
#pragma unroll
  for (int i = 0; i < 4; ++i)
    out[(size_t)(n0 + ty + i * 8) * K + (k0 + tx)] = f2bf(tile[tx][ty + i * 8]);
}

// C[M,N] = A[M,K](bf16) * Bt[N,K]^T(bf16) + bias. 128x128 tile, 4 waves (2x2 of 64x64).
// m97-verified structure + XCD-aware block swizzle.
// EPI 0: scatter q/k/v (q scaled 0.125; k,v XOR-swizzled; v transposed per head)
// EPI 1: fp32 output
template <int EPI>
__global__ __launch_bounds__(256, 2) void gemm128_kernel(
    const short* __restrict__ A, const short* __restrict__ Bt,
    const float* __restrict__ bias, float* __restrict__ foutp,
    short* __restrict__ q_out, short* __restrict__ k_out,
    short* __restrict__ v_out, int Mdim, int Ndim, int Kdim) {
  __shared__ __align__(16) short As[128 * 32];
  __shared__ __align__(16) short Bs[128 * 32];
  const int tid = threadIdx.x;
  const int lane = tid & 63;
  const int w = tid >> 6;
  const int wr = w >> 1, wc = w & 1;
  // XCD-aware swizzle (nwg % 8 == 0 for both grids)
  const int nwg = gridDim.x * gridDim.y;
  const int lin = blockIdx.y * gridDim.x + blockIdx.x;
  const int tile = (lin & 7) * (nwg >> 3) + (lin >> 3);
  const int row0 = (tile / gridDim.x) * 128;
  const int col0 = (tile % gridDim.x) * 128;
  const int lrow = lane & 15, lkg = lane >> 4;

  f32x4 acc[4][4];
#pragma unroll
  for (int i = 0; i < 4; ++i)
#pragma unroll
    for (int j = 0; j < 4; ++j) acc[i][j] = (f32x4){0.f, 0.f, 0.f, 0.f};

  const short* Ab = A + (size_t)row0 * Kdim;
  const short* Bb = Bt + (size_t)col0 * Kdim;
  const int sr = tid >> 2;
  const int sc = (tid & 3) * 8;

  for (int kt = 0; kt < Kdim; kt += 32) {
    gload16(Ab + (size_t)sr * Kdim + kt + sc, As + tid * 8);
    gload16(Ab + (size_t)(sr + 64) * Kdim + kt + sc, As + 2048 + tid * 8);
    gload16(Bb + (size_t)sr * Kdim + kt + sc, Bs + tid * 8);
    gload16(Bb + (size_t)(sr + 64) * Kdim + kt + sc, Bs + 2048 + tid * 8);
    __syncthreads();
    short8 af[4], bfr[4];
#pragma unroll
    for (int i = 0; i < 4; ++i)
      af[i] = *(const short8*)(As + (wr * 64 + i * 16 + lrow) * 32 + lkg * 8);
#pragma unroll
    for (int j = 0; j < 4; ++j)
      bfr[j] = *(const short8*)(Bs + (wc * 64 + j * 16 + lrow) * 32 + lkg * 8);
#pragma unroll
    for (int i = 0; i < 4; ++i)
#pragma unroll
      for (int j = 0; j < 4; ++j)
        acc[i][j] = __builtin_amdgcn_mfma_f32_16x16x32_bf16(af[i], bfr[j], acc[i][j], 0, 0, 0);
    __syncthreads();
  }

#pragma unroll
  for (int i = 0; i < 4; ++i) {
#pragma unroll
    for (int j = 0; j < 4; ++j) {
      const int gn = col0 + wc * 64 + j * 16 + lrow;
      const int gmb = row0 + wr * 64 + i * 16 + lkg * 4;  // +r<4 never crosses 2048
      float vr[4];
#pragma unroll
      for (int r = 0; r < 4; ++r) vr[r] = acc[i][j][r] + bias[gn];
      if (EPI == 0) {
        const int which = gn >> 10;
        const int hh = (gn >> 6) & 15;
        const int dd = gn & 63;
        const int b = gmb >> 11;
        const int tt0 = gmb & 2047;
        const size_t bh = (size_t)b * NHEADS + hh;
        if (which == 0) {
#pragma unroll
          for (int r = 0; r < 4; ++r)
            q_out[(bh * SEQ + tt0 + r) * HDIM + dd] = f2bf(vr[r] * 0.125f);
        } else if (which == 1) {
#pragma unroll
          for (int r = 0; r < 4; ++r)
            k_out[(bh * SEQ + tt0 + r) * HDIM + (dd ^ (((tt0 + r) & 7) << 3))] = f2bf(vr[r]);
        } else {
          // V^T: 4 consecutive tokens for fixed dim -> one 8B store
          short4v pk;
#pragma unroll
          for (int r = 0; r < 4; ++r) pk[r] = f2bf(vr[r]);
          *(short4v*)(v_out + (bh * HDIM + dd) * SEQ + (tt0 ^ ((dd & 7) << 3))) = pk;
        }
      } else {
#pragma unroll
        for (int r = 0; r < 4; ++r)
          foutp[(size_t)(gmb + r) * Ndim + gn] = vr[r];
      }
    }
  }
}

// causal flash attention; grid (SEQ/64=32, BHCNT); block = 2 waves x 32 q-rows.
// Single-buffered 16KB LDS -> 8-10 blocks/CU; TLP hides staging latency.
// Swapped QK^T in-register softmax; permlane P-relayout; exact rescale-skip.
__global__ __launch_bounds__(128, 5) void attn_kernel(
    const short* __restrict__ qb, const short* __restrict__ kb,
    const short* __restrict__ vb, short* __restrict__ aout) {
  __shared__ __align__(16) short Ks[64 * 64];
  __shared__ __align__(16) short Vs[64 * 64];
  const int tid = threadIdx.x;   // 0..127
  const int lane = tid & 63;
  const int w = tid >> 6;        // 0..1
  // XCD swizzle: 2048 blocks -> 256/XCD = 8 consecutive heads (K/V ~L2-resident)
  const int lin = blockIdx.y * gridDim.x + blockIdx.x;
  const int tile = ((lin & 7) << 8) + (lin >> 3);
  const int bh = tile >> 5;
  const int qblk = 31 - (tile & 31);  // heavy blocks first within each head
  const int q0 = qblk * 64;
  const int qw0 = q0 + w * 32;
  const int lrow = lane & 15, lkg = lane >> 4;

  const short* kbase = kb + (size_t)bh * SEQ * HDIM;
  const short* vbase = vb + (size_t)bh * HDIM * SEQ;

  short8 qf[2][2];
#pragma unroll
  for (int rb = 0; rb < 2; ++rb) {
    const short* qrow = qb + ((size_t)bh * SEQ + qw0 + rb * 16 + lrow) * HDIM;
    qf[rb][0] = *(const short8*)(qrow + lkg * 8);
    qf[rb][1] = *(const short8*)(qrow + 32 + lkg * 8);
  }

  f32x4 o[2][4];
  float mr[2], lsum[2];
#pragma unroll
  for (int rb = 0; rb < 2; ++rb) {
#pragma unroll
    for (int g = 0; g < 4; ++g) o[rb][g] = (f32x4){0.f, 0.f, 0.f, 0.f};
    mr[rb] = -__builtin_inff();
    lsum[rb] = 0.f;
  }

  const int ntile = qblk + 1;

  for (int it = 0; it < ntile; ++it) {
    const int kt = it * 64;
    __syncthreads();  // all waves done reading previous tile
    // stage K tile (4096 shorts) + V^T tile (64 rows x 64 tok), 128 threads
#pragma unroll
    for (int i = 0; i < 4; ++i)
      gload16(kbase + (size_t)kt * HDIM + i * 1024 + tid * 8, Ks + i * 1024 + tid * 8);
#pragma unroll
    for (int i = 0; i < 4; ++i)
      gload16(vbase + (size_t)(16 * i + (tid >> 3)) * SEQ + kt + (tid & 7) * 8,
              Vs + (16 * i + (tid >> 3)) * 64 + (tid & 7) * 8);
    __syncthreads();  // staged (vmcnt drained by barrier semantics)

    // QK^T swapped: s[rb][f][r] = S[q = qw0+rb*16+lrow][k = kt+f*16+lkg*4+r]
    f32x4 s[2][4];
#pragma unroll
    for (int rb = 0; rb < 2; ++rb)
#pragma unroll
      for (int f = 0; f < 4; ++f) s[rb][f] = (f32x4){0.f, 0.f, 0.f, 0.f};

    __builtin_amdgcn_s_setprio(1);
#pragma unroll
    for (int c = 0; c < 2; ++c) {
#pragma unroll
      for (int f = 0; f < 4; ++f) {
        const int krow = f * 16 + lrow;
        const int kel = (c * 32 + lkg * 8) ^ ((krow & 7) << 3);
        short8 kf = *(const short8*)(Ks + krow * 64 + kel);
        s[0][f] = __builtin_amdgcn_mfma_f32_16x16x32_bf16(kf, qf[0][c], s[0][f], 0, 0, 0);
        s[1][f] = __builtin_amdgcn_mfma_f32_16x16x32_bf16(kf, qf[1][c], s[1][f], 0, 0, 0);
      }
    }
    __builtin_amdgcn_s_setprio(0);

    if (kt + 63 > qw0) {  // diagonal region: causal mask (k > q -> -inf)
#pragma unroll
      for (int rb = 0; rb < 2; ++rb) {
        const int qq = qw0 + rb * 16 + lrow;
#pragma unroll
        for (int f = 0; f < 4; ++f) {
          const int kg = kt + f * 16 + lkg * 4;
#pragma unroll
          for (int r = 0; r < 4; ++r)
            if (kg + r > qq) s[rb][f][r] = -__builtin_inff();
        }
      }
    }

    const float L2E = 1.44269504088896340736f;
    float pm[2];
#pragma unroll
    for (int rb = 0; rb < 2; ++rb) {
      float p = fmaxf(fmaxf(fmaxf(s[rb][0][0], s[rb][0][1]), fmaxf(s[rb][0][2], s[rb][0][3])),
                      fmaxf(fmaxf(s[rb][1][0], s[rb][1][1]), fmaxf(s[rb][1][2], s[rb][1][3])));
      p = fmaxf(p, fmaxf(fmaxf(fmaxf(s[rb][2][0], s[rb][2][1]), fmaxf(s[rb][2][2], s[rb][2][3])),
                         fmaxf(fmaxf(s[rb][3][0], s[rb][3][1]), fmaxf(s[rb][3][2], s[rb][3][3]))));
      p = fmaxf(p, __shfl_xor(p, 16));
      p = fmaxf(p, __shfl_xor(p, 32));
      pm[rb] = p;
    }
    const float mn0 = fmaxf(mr[0], pm[0]);
    const float mn1 = fmaxf(mr[1], pm[1]);
    // exact skip: if no row's max grew, every alpha == 1 -> no rescale needed
    if (!__all(pm[0] <= mr[0] && pm[1] <= mr[1])) {
      const float a0 = fast_exp2((mr[0] - mn0) * L2E);
      const float a1 = fast_exp2((mr[1] - mn1) * L2E);
      lsum[0] *= a0;
      lsum[1] *= a1;
#pragma unroll
      for (int r = 0; r < 4; ++r) {
        const float s0 = __shfl(a0, lkg * 4 + r, 16);
        const float s1 = __shfl(a1, lkg * 4 + r, 16);
#pragma unroll
        for (int g = 0; g < 4; ++g) { o[0][g][r] *= s0; o[1][g][r] *= s1; }
      }
    }
    mr[0] = mn0; mr[1] = mn1;

    unsigned int q32[2][4][2];
#pragma unroll
    for (int rb = 0; rb < 2; ++rb) {
      const float mn = rb ? mn1 : mn0;
      float rs = 0.f;
#pragma unroll
      for (int f = 0; f < 4; ++f)
#pragma unroll
        for (int r = 0; r < 4; ++r) {
          const float p = fast_exp2((s[rb][f][r] - mn) * L2E);
          s[rb][f][r] = p;
          rs += p;
        }
      rs += __shfl_xor(rs, 16);
      rs += __shfl_xor(rs, 32);
      lsum[rb] += rs;
#pragma unroll
      for (int f = 0; f < 4; ++f) {
        q32[rb][f][0] = pack_bf16(s[rb][f][0], s[rb][f][1]);
        q32[rb][f][1] = pack_bf16(s[rb][f][2], s[rb][f][3]);
      }
    }

    // O += P*V ; P A-frags assembled in-register via permlane swaps
    __builtin_amdgcn_s_setprio(1);
#pragma unroll
    for (int c = 0; c < 2; ++c) {
      uint4v pw0, pw1;
#pragma unroll
      for (int h = 0; h < 2; ++h) {
        unsigned int a0 = q32[0][2 * c][h], b0 = q32[0][2 * c + 1][h];
        permlane32_swap(a0, b0);
        permlane16_swap(a0, b0);
        pw0[h] = a0; pw0[2 + h] = b0;
        unsigned int a1 = q32[1][2 * c][h], b1 = q32[1][2 * c + 1][h];
        permlane32_swap(a1, b1);
        permlane16_swap(a1, b1);
        pw1[h] = a1; pw1[2 + h] = b1;
      }
      const short8 pf0 = __builtin_bit_cast(short8, pw0);
      const short8 pf1 = __builtin_bit_cast(short8, pw1);
#pragma unroll
      for (int g = 0; g < 4; ++g) {
        const int vrow = g * 16 + lrow;
        const int vel = (c * 32 + lkg * 8) ^ ((vrow & 7) << 3);
        short8 vf = *(const short8*)(Vs + vrow * 64 + vel);
        o[0][g] = __builtin_amdgcn_mfma_f32_16x16x32_bf16(pf0, vf, o[0][g], 0, 0, 0);
        o[1][g] = __builtin_amdgcn_mfma_f32_16x16x32_bf16(pf1, vf, o[1][g], 0, 0, 0);
      }
    }
    __builtin_amdgcn_s_setprio(0);
  }

  const int b = bh >> 4, h = bh & 15;
  const float li0 = 1.0f / lsum[0];
  const float li1 = 1.0f / lsum[1];
#pragma unroll
  for (int r = 0; r < 4; ++r) {
    const float i0 = __shfl(li0, lkg * 4 + r, 16);
    const float i1 = __shfl(li1, lkg * 4 + r, 16);
    const int t0 = qw0 + lkg * 4 + r;
#pragma unroll
    for (int g = 0; g < 4; ++g) {
      aout[((size_t)b * SEQ + t0) * DMODEL + h * 64 + g * 16 + lrow] = f2bf(o[0][g][r] * i0);
      aout[((size_t)b * SEQ + t0 + 16) * DMODEL + h * 64 + g * 16 + lrow] = f2bf(o[1][g][r] * i1);
    }
  }
}

extern "C" void kernel_launch(void* const* d_in, const int* in_sizes, int n_in,
                              void* d_out, int out_size, void* d_ws, size_t ws_size,
                              hipStream_t stream) {
  const float* x = (const float*)d_in[0];
  // d_in[1] = mask (causal tril) — hardcoded in attn kernel
  const float* Wqkv = (const float*)d_in[2];
  const float* bqkv = (const float*)d_in[3];
  const float* Wout = (const float*)d_in[4];
  const float* bout = (const float*)d_in[5];

  char* ws = (char*)d_ws;
  short* xb    = (short*)(ws + 0);         // 16,777,216 B
  short* wqkvT = (short*)(ws + 16777216);  //  6,291,456 B
  short* woutT = (short*)(ws + 23068672);  //  2,097,152 B
  short* qbuf  = (short*)(ws + 25165824);  // 16,777,216 B
  short* kbuf  = (short*)(ws + 41943040);  // 16,777,216 B (row-swizzled)
  short* vbuf  = (short*)(ws + 58720256);  // 16,777,216 B (V^T per head, swizzled)
  short* abuf  = (short*)(ws + 75497472);  // 16,777,216 B — total 92,274,688 B

  cast_x_kernel<<<(MROWS * DMODEL) / 4 / 256, 256, 0, stream>>>(x, xb, MROWS * DMODEL);
  transpose_cast_kernel<<<dim3(N3 / 32, DMODEL / 32), dim3(32, 8), 0, stream>>>(
      Wqkv, wqkvT, DMODEL, N3);
  transpose_cast_kernel<<<dim3(DMODEL / 32, DMODEL / 32), dim3(32, 8), 0, stream>>>(
      Wout, woutT, DMODEL, DMODEL);
  gemm128_kernel<0><<<dim3(N3 / 128, MROWS / 128), 256, 0, stream>>>(
      xb, wqkvT, bqkv, nullptr, qbuf, kbuf, vbuf, MROWS, N3, DMODEL);
  attn_kernel<<<dim3(SEQ / 64, BHCNT), 128, 0, stream>>>(qbuf, kbuf, vbuf, abuf);
  gemm128_kernel<1><<<dim3(DMODEL / 128, MROWS / 128), 256, 0, stream>>>(
      abuf, woutT, bout, (float*)d_out, nullptr, nullptr, nullptr, MROWS, DMODEL, DMODEL);
}

// Round 10
// 317.523 us; speedup vs baseline: 1.2937x; 1.2937x over previous
//
#include <hip/hip_runtime.h>
#include <hip/hip_bf16.h>
#include <cstdint>
#include <cstddef>

#define DMODEL 1024
#define NHEADS 16
#define HDIM 64
#define BATCH 4
#define SEQ 2048
#define MROWS (BATCH*SEQ)   // 8192
#define N3 (3*DMODEL)       // 3072
#define BHCNT (BATCH*NHEADS) // 64

typedef __attribute__((ext_vector_type(8))) short short8;
typedef __attribute__((ext_vector_type(4))) short short4v;
typedef __attribute__((ext_vector_type(4))) float f32x4;
typedef __attribute__((ext_vector_type(4))) unsigned int uint4v;

// round-to-nearest-even f32 -> bf16 (data has no NaN)
static __device__ __forceinline__ short f2bf(float f) {
  unsigned int u = __builtin_bit_cast(unsigned int, f);
  return (short)((u + 0x7fffu + ((u >> 16) & 1u)) >> 16);
}

// pack two f32 -> one u32 of 2 bf16 (lo, hi) via gfx950 v_cvt_pk_bf16_f32
static __device__ __forceinline__ unsigned int pack_bf16(float lo, float hi) {
  unsigned int r;
  asm("v_cvt_pk_bf16_f32 %0, %1, %2" : "=v"(r) : "v"(lo), "v"(hi));
  return r;
}

// gfx950 fragment-transform swaps:
// permlane32_swap: a.hi32 <-> b.lo32  =>  a'={a.lo,b.lo}, b'={a.hi,b.hi}
// permlane16_swap: a.g1<->b.g0, a.g3<->b.g2 (16-lane groups)
static __device__ __forceinline__ void permlane32_swap(unsigned int& a, unsigned int& b) {
  asm("v_permlane32_swap_b32 %0, %1" : "+v"(a), "+v"(b));
}
static __device__ __forceinline__ void permlane16_swap(unsigned int& a, unsigned int& b) {
  asm("v_permlane16_swap_b32 %0, %1" : "+v"(a), "+v"(b));
}

static __device__ __forceinline__ float fast_exp2(float x) {
#if __has_builtin(__builtin_amdgcn_exp2f)
  return __builtin_amdgcn_exp2f(x);
#else
  return exp2f(x);
#endif
}

static __device__ __forceinline__ void gload16(const void* g, void* l) {
  __builtin_amdgcn_global_load_lds(
      (const __attribute__((address_space(1))) unsigned int*)g,
      (__attribute__((address_space(3))) unsigned int*)l, 16, 0, 0);
}

__global__ __launch_bounds__(256) void cast_x_kernel(
    const float* __restrict__ in, short* __restrict__ out, int n) {
  int i = (blockIdx.x * 256 + threadIdx.x) * 4;
  if (i + 3 < n) {
    float4 v = *(const float4*)(in + i);
    short4v s;
    s[0] = f2bf(v.x); s[1] = f2bf(v.y); s[2] = f2bf(v.z); s[3] = f2bf(v.w);
    *(short4v*)(out + i) = s;
  }
}

// in [K][N] f32 row-major -> out [N][K] bf16 row-major
__global__ __launch_bounds__(256) void transpose_cast_kernel(
    const float* __restrict__ in, short* __restrict__ out, int K, int N) {
  __shared__ float tile[32][33];
  int n0 = blockIdx.x * 32, k0 = blockIdx.y * 32;
  int tx = threadIdx.x, ty = threadIdx.y;  // 32 x 8
#pragma unroll
  for (int i = 0; i < 4; ++i)
    tile[ty + i * 8][tx] = in[(size_t)(k0 + ty + i * 8) * N + (n0 + tx)];
  __syncthreads();
#pragma unroll
  for (int i = 0; i < 4; ++i)
    out[(size_t)(n0 + ty + i * 8) * K + (k0 + tx)] = f2bf(tile[tx][ty + i * 8]);
}

// C[M,N] = A[M,K](bf16) * Bt[N,K]^T(bf16) + bias. 128x128 tile, 4 waves (2x2 of 64x64).
// m97-verified structure + XCD-aware block swizzle.
// EPI 0: scatter q/k/v (q scaled 0.125; k,v XOR-swizzled; v transposed per head)
// EPI 1: fp32 output
template <int EPI>
__global__ __launch_bounds__(256, 2) void gemm128_kernel(
    const short* __restrict__ A, const short* __restrict__ Bt,
    const float* __restrict__ bias, float* __restrict__ foutp,
    short* __restrict__ q_out, short* __restrict__ k_out,
    short* __restrict__ v_out, int Mdim, int Ndim, int Kdim) {
  __shared__ __align__(16) short As[128 * 32];
  __shared__ __align__(16) short Bs[128 * 32];
  const int tid = threadIdx.x;
  const int lane = tid & 63;
  const int w = tid >> 6;
  const int wr = w >> 1, wc = w & 1;
  // XCD-aware swizzle (nwg % 8 == 0 for both grids)
  const int nwg = gridDim.x * gridDim.y;
  const int lin = blockIdx.y * gridDim.x + blockIdx.x;
  const int tile = (lin & 7) * (nwg >> 3) + (lin >> 3);
  const int row0 = (tile / gridDim.x) * 128;
  const int col0 = (tile % gridDim.x) * 128;
  const int lrow = lane & 15, lkg = lane >> 4;

  f32x4 acc[4][4];
#pragma unroll
  for (int i = 0; i < 4; ++i)
#pragma unroll
    for (int j = 0; j < 4; ++j) acc[i][j] = (f32x4){0.f, 0.f, 0.f, 0.f};

  const short* Ab = A + (size_t)row0 * Kdim;
  const short* Bb = Bt + (size_t)col0 * Kdim;
  const int sr = tid >> 2;
  const int sc = (tid & 3) * 8;

  for (int kt = 0; kt < Kdim; kt += 32) {
    gload16(Ab + (size_t)sr * Kdim + kt + sc, As + tid * 8);
    gload16(Ab + (size_t)(sr + 64) * Kdim + kt + sc, As + 2048 + tid * 8);
    gload16(Bb + (size_t)sr * Kdim + kt + sc, Bs + tid * 8);
    gload16(Bb + (size_t)(sr + 64) * Kdim + kt + sc, Bs + 2048 + tid * 8);
    __syncthreads();
    short8 af[4], bfr[4];
#pragma unroll
    for (int i = 0; i < 4; ++i)
      af[i] = *(const short8*)(As + (wr * 64 + i * 16 + lrow) * 32 + lkg * 8);
#pragma unroll
    for (int j = 0; j < 4; ++j)
      bfr[j] = *(const short8*)(Bs + (wc * 64 + j * 16 + lrow) * 32 + lkg * 8);
#pragma unroll
    for (int i = 0; i < 4; ++i)
#pragma unroll
      for (int j = 0; j < 4; ++j)
        acc[i][j] = __builtin_amdgcn_mfma_f32_16x16x32_bf16(af[i], bfr[j], acc[i][j], 0, 0, 0);
    __syncthreads();
  }

#pragma unroll
  for (int i = 0; i < 4; ++i) {
#pragma unroll
    for (int j = 0; j < 4; ++j) {
      const int gn = col0 + wc * 64 + j * 16 + lrow;
      const int gmb = row0 + wr * 64 + i * 16 + lkg * 4;  // +r<4 never crosses 2048
      float vr[4];
#pragma unroll
      for (int r = 0; r < 4; ++r) vr[r] = acc[i][j][r] + bias[gn];
      if (EPI == 0) {
        const int which = gn >> 10;
        const int hh = (gn >> 6) & 15;
        const int dd = gn & 63;
        const int b = gmb >> 11;
        const int tt0 = gmb & 2047;
        const size_t bh = (size_t)b * NHEADS + hh;
        if (which == 0) {
#pragma unroll
          for (int r = 0; r < 4; ++r)
            q_out[(bh * SEQ + tt0 + r) * HDIM + dd] = f2bf(vr[r] * 0.125f);
        } else if (which == 1) {
#pragma unroll
          for (int r = 0; r < 4; ++r)
            k_out[(bh * SEQ + tt0 + r) * HDIM + (dd ^ (((tt0 + r) & 7) << 3))] = f2bf(vr[r]);
        } else {
          // V^T: 4 consecutive tokens for fixed dim -> one 8B store
          short4v pk;
#pragma unroll
          for (int r = 0; r < 4; ++r) pk[r] = f2bf(vr[r]);
          *(short4v*)(v_out + (bh * HDIM + dd) * SEQ + (tt0 ^ ((dd & 7) << 3))) = pk;
        }
      } else {
#pragma unroll
        for (int r = 0; r < 4; ++r)
          foutp[(size_t)(gmb + r) * Ndim + gn] = vr[r];
      }
    }
  }
}

// causal flash attention; grid (SEQ/64=32, BHCNT); block = 2 waves x 32 q-rows.
// Single-buffered 16KB LDS; TLP hides staging latency.
// launch_bounds(128,4): VGPR cap 128 — (128,5) capped at ~96 and spilled the
// accumulators to scratch (+240MB HBM round-trip, R6 post-mortem). R5 proves
// the register state fits at a 128-reg cap without spill.
__global__ __launch_bounds__(128, 4) void attn_kernel(
    const short* __restrict__ qb, const short* __restrict__ kb,
    const short* __restrict__ vb, short* __restrict__ aout) {
  __shared__ __align__(16) short Ks[64 * 64];
  __shared__ __align__(16) short Vs[64 * 64];
  const int tid = threadIdx.x;   // 0..127
  const int lane = tid & 63;
  const int w = tid >> 6;        // 0..1
  // XCD swizzle: 2048 blocks -> 256/XCD = 8 consecutive heads (K/V ~L2-resident)
  const int lin = blockIdx.y * gridDim.x + blockIdx.x;
  const int tile = ((lin & 7) << 8) + (lin >> 3);
  const int bh = tile >> 5;
  const int qblk = 31 - (tile & 31);  // heavy blocks first within each head
  const int q0 = qblk * 64;
  const int qw0 = q0 + w * 32;
  const int lrow = lane & 15, lkg = lane >> 4;

  const short* kbase = kb + (size_t)bh * SEQ * HDIM;
  const short* vbase = vb + (size_t)bh * HDIM * SEQ;

  short8 qf[2][2];
#pragma unroll
  for (int rb = 0; rb < 2; ++rb) {
    const short* qrow = qb + ((size_t)bh * SEQ + qw0 + rb * 16 + lrow) * HDIM;
    qf[rb][0] = *(const short8*)(qrow + lkg * 8);
    qf[rb][1] = *(const short8*)(qrow + 32 + lkg * 8);
  }

  f32x4 o[2][4];
  float mr[2], lsum[2];
#pragma unroll
  for (int rb = 0; rb < 2; ++rb) {
#pragma unroll
    for (int g = 0; g < 4; ++g) o[rb][g] = (f32x4){0.f, 0.f, 0.f, 0.f};
    mr[rb] = -__builtin_inff();
    lsum[rb] = 0.f;
  }

  const int ntile = qblk + 1;

  for (int it = 0; it < ntile; ++it) {
    const int kt = it * 64;
    __syncthreads();  // all waves done reading previous tile
    // stage K tile (4096 shorts) + V^T tile (64 rows x 64 tok), 128 threads
#pragma unroll
    for (int i = 0; i < 4; ++i)
      gload16(kbase + (size_t)kt * HDIM + i * 1024 + tid * 8, Ks + i * 1024 + tid * 8);
#pragma unroll
    for (int i = 0; i < 4; ++i)
      gload16(vbase + (size_t)(16 * i + (tid >> 3)) * SEQ + kt + (tid & 7) * 8,
              Vs + (16 * i + (tid >> 3)) * 64 + (tid & 7) * 8);
    __syncthreads();  // staged (vmcnt drained by barrier semantics)

    // QK^T swapped: s[rb][f][r] = S[q = qw0+rb*16+lrow][k = kt+f*16+lkg*4+r]
    f32x4 s[2][4];
#pragma unroll
    for (int rb = 0; rb < 2; ++rb)
#pragma unroll
      for (int f = 0; f < 4; ++f) s[rb][f] = (f32x4){0.f, 0.f, 0.f, 0.f};

    __builtin_amdgcn_s_setprio(1);
#pragma unroll
    for (int c = 0; c < 2; ++c) {
#pragma unroll
      for (int f = 0; f < 4; ++f) {
        const int krow = f * 16 + lrow;
        const int kel = (c * 32 + lkg * 8) ^ ((krow & 7) << 3);
        short8 kf = *(const short8*)(Ks + krow * 64 + kel);
        s[0][f] = __builtin_amdgcn_mfma_f32_16x16x32_bf16(kf, qf[0][c], s[0][f], 0, 0, 0);
        s[1][f] = __builtin_amdgcn_mfma_f32_16x16x32_bf16(kf, qf[1][c], s[1][f], 0, 0, 0);
      }
    }
    __builtin_amdgcn_s_setprio(0);

    if (kt + 63 > qw0) {  // diagonal region: causal mask (k > q -> -inf)
#pragma unroll
      for (int rb = 0; rb < 2; ++rb) {
        const int qq = qw0 + rb * 16 + lrow;
#pragma unroll
        for (int f = 0; f < 4; ++f) {
          const int kg = kt + f * 16 + lkg * 4;
#pragma unroll
          for (int r = 0; r < 4; ++r)
            if (kg + r > qq) s[rb][f][r] = -__builtin_inff();
        }
      }
    }

    const float L2E = 1.44269504088896340736f;
    float pm[2];
#pragma unroll
    for (int rb = 0; rb < 2; ++rb) {
      float p = fmaxf(fmaxf(fmaxf(s[rb][0][0], s[rb][0][1]), fmaxf(s[rb][0][2], s[rb][0][3])),
                      fmaxf(fmaxf(s[rb][1][0], s[rb][1][1]), fmaxf(s[rb][1][2], s[rb][1][3])));
      p = fmaxf(p, fmaxf(fmaxf(fmaxf(s[rb][2][0], s[rb][2][1]), fmaxf(s[rb][2][2], s[rb][2][3])),
                         fmaxf(fmaxf(s[rb][3][0], s[rb][3][1]), fmaxf(s[rb][3][2], s[rb][3][3]))));
      p = fmaxf(p, __shfl_xor(p, 16));
      p = fmaxf(p, __shfl_xor(p, 32));
      pm[rb] = p;
    }
    const float mn0 = fmaxf(mr[0], pm[0]);
    const float mn1 = fmaxf(mr[1], pm[1]);
    // exact skip: if no row's max grew, every alpha == 1 -> no rescale needed
    if (!__all(pm[0] <= mr[0] && pm[1] <= mr[1])) {
      const float a0 = fast_exp2((mr[0] - mn0) * L2E);
      const float a1 = fast_exp2((mr[1] - mn1) * L2E);
      lsum[0] *= a0;
      lsum[1] *= a1;
#pragma unroll
      for (int r = 0; r < 4; ++r) {
        const float s0 = __shfl(a0, lkg * 4 + r, 16);
        const float s1 = __shfl(a1, lkg * 4 + r, 16);
#pragma unroll
        for (int g = 0; g < 4; ++g) { o[0][g][r] *= s0; o[1][g][r] *= s1; }
      }
    }
    mr[0] = mn0; mr[1] = mn1;

    unsigned int q32[2][4][2];
#pragma unroll
    for (int rb = 0; rb < 2; ++rb) {
      const float mn = rb ? mn1 : mn0;
      float rs = 0.f;
#pragma unroll
      for (int f = 0; f < 4; ++f)
#pragma unroll
        for (int r = 0; r < 4; ++r) {
          const float p = fast_exp2((s[rb][f][r] - mn) * L2E);
          s[rb][f][r] = p;
          rs += p;
        }
      rs += __shfl_xor(rs, 16);
      rs += __shfl_xor(rs, 32);
      lsum[rb] += rs;
#pragma unroll
      for (int f = 0; f < 4; ++f) {
        q32[rb][f][0] = pack_bf16(s[rb][f][0], s[rb][f][1]);
        q32[rb][f][1] = pack_bf16(s[rb][f][2], s[rb][f][3]);
      }
    }

    // O += P*V ; P A-frags assembled in-register via permlane swaps
    __builtin_amdgcn_s_setprio(1);
#pragma unroll
    for (int c = 0; c < 2; ++c) {
      uint4v pw0, pw1;
#pragma unroll
      for (int h = 0; h < 2; ++h) {
        unsigned int a0 = q32[0][2 * c][h], b0 = q32[0][2 * c + 1][h];
        permlane32_swap(a0, b0);
        permlane16_swap(a0, b0);
        pw0[h] = a0; pw0[2 + h] = b0;
        unsigned int a1 = q32[1][2 * c][h], b1 = q32[1][2 * c + 1][h];
        permlane32_swap(a1, b1);
        permlane16_swap(a1, b1);
        pw1[h] = a1; pw1[2 + h] = b1;
      }
      const short8 pf0 = __builtin_bit_cast(short8, pw0);
      const short8 pf1 = __builtin_bit_cast(short8, pw1);
#pragma unroll
      for (int g = 0; g < 4; ++g) {
        const int vrow = g * 16 + lrow;
        const int vel = (c * 32 + lkg * 8) ^ ((vrow & 7) << 3);
        short8 vf = *(const short8*)(Vs + vrow * 64 + vel);
        o[0][g] = __builtin_amdgcn_mfma_f32_16x16x32_bf16(pf0, vf, o[0][g], 0, 0, 0);
        o[1][g] = __builtin_amdgcn_mfma_f32_16x16x32_bf16(pf1, vf, o[1][g], 0, 0, 0);
      }
    }
    __builtin_amdgcn_s_setprio(0);
  }

  const int b = bh >> 4, h = bh & 15;
  const float li0 = 1.0f / lsum[0];
  const float li1 = 1.0f / lsum[1];
#pragma unroll
  for (int r = 0; r < 4; ++r) {
    const float i0 = __shfl(li0, lkg * 4 + r, 16);
    const float i1 = __shfl(li1, lkg * 4 + r, 16);
    const int t0 = qw0 + lkg * 4 + r;
#pragma unroll
    for (int g = 0; g < 4; ++g) {
      aout[((size_t)b * SEQ + t0) * DMODEL + h * 64 + g * 16 + lrow] = f2bf(o[0][g][r] * i0);
      aout[((size_t)b * SEQ + t0 + 16) * DMODEL + h * 64 + g * 16 + lrow] = f2bf(o[1][g][r] * i1);
    }
  }
}

extern "C" void kernel_launch(void* const* d_in, const int* in_sizes, int n_in,
                              void* d_out, int out_size, void* d_ws, size_t ws_size,
                              hipStream_t stream) {
  const float* x = (const float*)d_in[0];
  // d_in[1] = mask (causal tril) — hardcoded in attn kernel
  const float* Wqkv = (const float*)d_in[2];
  const float* bqkv = (const float*)d_in[3];
  const float* Wout = (const float*)d_in[4];
  const float* bout = (const float*)d_in[5];

  char* ws = (char*)d_ws;
  short* xb    = (short*)(ws + 0);         // 16,777,216 B
  short* wqkvT = (short*)(ws + 16777216);  //  6,291,456 B
  short* woutT = (short*)(ws + 23068672);  //  2,097,152 B
  short* qbuf  = (short*)(ws + 25165824);  // 16,777,216 B
  short* kbuf  = (short*)(ws + 41943040);  // 16,777,216 B (row-swizzled)
  short* vbuf  = (short*)(ws + 58720256);  // 16,777,216 B (V^T per head, swizzled)
  short* abuf  = (short*)(ws + 75497472);  // 16,777,216 B — total 92,274,688 B

  cast_x_kernel<<<(MROWS * DMODEL) / 4 / 256, 256, 0, stream>>>(x, xb, MROWS * DMODEL);
  transpose_cast_kernel<<<dim3(N3 / 32, DMODEL / 32), dim3(32, 8), 0, stream>>>(
      Wqkv, wqkvT, DMODEL, N3);
  transpose_cast_kernel<<<dim3(DMODEL / 32, DMODEL / 32), dim3(32, 8), 0, stream>>>(
      Wout, woutT, DMODEL, DMODEL);
  gemm128_kernel<0><<<dim3(N3 / 128, MROWS / 128), 256, 0, stream>>>(
      xb, wqkvT, bqkv, nullptr, qbuf, kbuf, vbuf, MROWS, N3, DMODEL);
  attn_kernel<<<dim3(SEQ / 64, BHCNT), 128, 0, stream>>>(qbuf, kbuf, vbuf, abuf);
  gemm128_kernel<1><<<dim3(DMODEL / 128, MROWS / 128), 256, 0, stream>>>(
      abuf, woutT, bout, (float*)d_out, nullptr, nullptr, nullptr, MROWS, DMODEL, DMODEL);
}

// Round 11
// 293.658 us; speedup vs baseline: 1.3988x; 1.0813x over previous
//
#include <hip/hip_runtime.h>
#include <hip/hip_bf16.h>
#include <cstdint>
#include <cstddef>

#define DMODEL 1024
#define NHEADS 16
#define HDIM 64
#define BATCH 4
#define SEQ 2048
#define MROWS (BATCH*SEQ)   // 8192
#define N3 (3*DMODEL)       // 3072
#define BHCNT (BATCH*NHEADS) // 64

typedef __attribute__((ext_vector_type(8))) short short8;
typedef __attribute__((ext_vector_type(4))) short short4v;
typedef __attribute__((ext_vector_type(4))) float f32x4;
typedef __attribute__((ext_vector_type(4))) unsigned int uint4v;

// round-to-nearest-even f32 -> bf16 (data has no NaN)
static __device__ __forceinline__ short f2bf(float f) {
  unsigned int u = __builtin_bit_cast(unsigned int, f);
  return (short)((u + 0x7fffu + ((u >> 16) & 1u)) >> 16);
}

// pack two f32 -> one u32 of 2 bf16 (lo, hi) via gfx950 v_cvt_pk_bf16_f32
static __device__ __forceinline__ unsigned int pack_bf16(float lo, float hi) {
  unsigned int r;
  asm("v_cvt_pk_bf16_f32 %0, %1, %2" : "=v"(r) : "v"(lo), "v"(hi));
  return r;
}

// gfx950 fragment-transform swaps
static __device__ __forceinline__ void permlane32_swap(unsigned int& a, unsigned int& b) {
  asm("v_permlane32_swap_b32 %0, %1" : "+v"(a), "+v"(b));
}
static __device__ __forceinline__ void permlane16_swap(unsigned int& a, unsigned int& b) {
  asm("v_permlane16_swap_b32 %0, %1" : "+v"(a), "+v"(b));
}

static __device__ __forceinline__ float fast_exp2(float x) {
#if __has_builtin(__builtin_amdgcn_exp2f)
  return __builtin_amdgcn_exp2f(x);
#else
  return exp2f(x);
#endif
}

static __device__ __forceinline__ void gload16(const void* g, void* l) {
  __builtin_amdgcn_global_load_lds(
      (const __attribute__((address_space(1))) unsigned int*)g,
      (__attribute__((address_space(3))) unsigned int*)l, 16, 0, 0);
}

__global__ __launch_bounds__(256) void cast_x_kernel(
    const float* __restrict__ in, short* __restrict__ out, int n) {
  int i = (blockIdx.x * 256 + threadIdx.x) * 4;
  if (i + 3 < n) {
    float4 v = *(const float4*)(in + i);
    short4v s;
    s[0] = f2bf(v.x); s[1] = f2bf(v.y); s[2] = f2bf(v.z); s[3] = f2bf(v.w);
    *(short4v*)(out + i) = s;
  }
}

// in [K][N] f32 row-major -> out [N][K] bf16 row-major
__global__ __launch_bounds__(256) void transpose_cast_kernel(
    const float* __restrict__ in, short* __restrict__ out, int K, int N) {
  __shared__ float tile[32][33];
  int n0 = blockIdx.x * 32, k0 = blockIdx.y * 32;
  int tx = threadIdx.x, ty = threadIdx.y;  // 32 x 8
#pragma unroll
  for (int i = 0; i < 4; ++i)
    tile[ty + i * 8][tx] = in[(size_t)(k0 + ty + i * 8) * N + (n0 + tx)];
  __syncthreads();
#pragma unroll
  for (int i = 0; i < 4; ++i)
    out[(size_t)(n0 + ty + i * 8) * K + (k0 + tx)] = f2bf(tile[tx][ty + i * 8]);
}

// C[M,N] = A[M,K](bf16) * Bt[N,K]^T(bf16) + bias. 128x128 tile, 4 waves (2x2 of 64x64).
// m97-verified structure + XCD-aware block swizzle.
// EPI 0: scatter q/k/v (q scaled 0.125; k,v XOR-swizzled; v transposed per head)
// EPI 1: fp32 output
template <int EPI>
__global__ __launch_bounds__(256, 2) void gemm128_kernel(
    const short* __restrict__ A, const short* __restrict__ Bt,
    const float* __restrict__ bias, float* __restrict__ foutp,
    short* __restrict__ q_out, short* __restrict__ k_out,
    short* __restrict__ v_out, int Mdim, int Ndim, int Kdim) {
  __shared__ __align__(16) short As[128 * 32];
  __shared__ __align__(16) short Bs[128 * 32];
  const int tid = threadIdx.x;
  const int lane = tid & 63;
  const int w = tid >> 6;
  const int wr = w >> 1, wc = w & 1;
  // XCD-aware swizzle (nwg % 8 == 0 for both grids)
  const int nwg = gridDim.x * gridDim.y;
  const int lin = blockIdx.y * gridDim.x + blockIdx.x;
  const int tile = (lin & 7) * (nwg >> 3) + (lin >> 3);
  const int row0 = (tile / gridDim.x) * 128;
  const int col0 = (tile % gridDim.x) * 128;
  const int lrow = lane & 15, lkg = lane >> 4;

  f32x4 acc[4][4];
#pragma unroll
  for (int i = 0; i < 4; ++i)
#pragma unroll
    for (int j = 0; j < 4; ++j) acc[i][j] = (f32x4){0.f, 0.f, 0.f, 0.f};

  const short* Ab = A + (size_t)row0 * Kdim;
  const short* Bb = Bt + (size_t)col0 * Kdim;
  const int sr = tid >> 2;
  const int sc = (tid & 3) * 8;

  for (int kt = 0; kt < Kdim; kt += 32) {
    gload16(Ab + (size_t)sr * Kdim + kt + sc, As + tid * 8);
    gload16(Ab + (size_t)(sr + 64) * Kdim + kt + sc, As + 2048 + tid * 8);
    gload16(Bb + (size_t)sr * Kdim + kt + sc, Bs + tid * 8);
    gload16(Bb + (size_t)(sr + 64) * Kdim + kt + sc, Bs + 2048 + tid * 8);
    __syncthreads();
    short8 af[4], bfr[4];
#pragma unroll
    for (int i = 0; i < 4; ++i)
      af[i] = *(const short8*)(As + (wr * 64 + i * 16 + lrow) * 32 + lkg * 8);
#pragma unroll
    for (int j = 0; j < 4; ++j)
      bfr[j] = *(const short8*)(Bs + (wc * 64 + j * 16 + lrow) * 32 + lkg * 8);
#pragma unroll
    for (int i = 0; i < 4; ++i)
#pragma unroll
      for (int j = 0; j < 4; ++j)
        acc[i][j] = __builtin_amdgcn_mfma_f32_16x16x32_bf16(af[i], bfr[j], acc[i][j], 0, 0, 0);
    __syncthreads();
  }

#pragma unroll
  for (int i = 0; i < 4; ++i) {
#pragma unroll
    for (int j = 0; j < 4; ++j) {
      const int gn = col0 + wc * 64 + j * 16 + lrow;
      const int gmb = row0 + wr * 64 + i * 16 + lkg * 4;  // +r<4 never crosses 2048
      float vr[4];
#pragma unroll
      for (int r = 0; r < 4; ++r) vr[r] = acc[i][j][r] + bias[gn];
      if (EPI == 0) {
        const int which = gn >> 10;
        const int hh = (gn >> 6) & 15;
        const int dd = gn & 63;
        const int b = gmb >> 11;
        const int tt0 = gmb & 2047;
        const size_t bh = (size_t)b * NHEADS + hh;
        if (which == 0) {
#pragma unroll
          for (int r = 0; r < 4; ++r)
            q_out[(bh * SEQ + tt0 + r) * HDIM + dd] = f2bf(vr[r] * 0.125f);
        } else if (which == 1) {
#pragma unroll
          for (int r = 0; r < 4; ++r)
            k_out[(bh * SEQ + tt0 + r) * HDIM + (dd ^ (((tt0 + r) & 7) << 3))] = f2bf(vr[r]);
        } else {
          // V^T: 4 consecutive tokens for fixed dim -> one 8B store
          short4v pk;
#pragma unroll
          for (int r = 0; r < 4; ++r) pk[r] = f2bf(vr[r]);
          *(short4v*)(v_out + (bh * HDIM + dd) * SEQ + (tt0 ^ ((dd & 7) << 3))) = pk;
        }
      } else {
#pragma unroll
        for (int r = 0; r < 4; ++r)
          foutp[(size_t)(gmb + r) * Ndim + gn] = vr[r];
      }
    }
  }
}

// causal flash attention, PAIRED q-tiles: block = 4 waves; waves 0-1 own heavy
// q-tile (31-i), waves 2-3 own light q-tile (i). One shared KV sweep of 32-i
// tiles serves both (light's range is a prefix of heavy's) -> 26% fewer
// block-tile iterations than unpaired, near-balanced block durations.
// grid 1024 blocks (16 pairs x 64 bh); 16KB single-buffer LDS.
__global__ __launch_bounds__(256, 4) void attn_kernel(
    const short* __restrict__ qb, const short* __restrict__ kb,
    const short* __restrict__ vb, short* __restrict__ aout) {
  __shared__ __align__(16) short Ks[64 * 64];
  __shared__ __align__(16) short Vs[64 * 64];
  const int tid = threadIdx.x;   // 0..255
  const int lane = tid & 63;
  const int w = tid >> 6;        // 0..3
  // XCD swizzle: 1024 blocks -> 128/XCD = 8 consecutive heads (K/V ~L2-resident)
  const int lin = blockIdx.y * gridDim.x + blockIdx.x;
  const int tile = ((lin & 7) << 7) + (lin >> 3);
  const int bh = tile >> 4;
  const int ip = tile & 15;            // pair index; ip=0 (heaviest) first
  const int heavy_q0 = (31 - ip) * 64;
  const int light_q0 = ip * 64;
  const int qw0 = (w < 2) ? heavy_q0 + w * 32 : light_q0 + (w - 2) * 32;
  const int lrow = lane & 15, lkg = lane >> 4;

  const short* kbase = kb + (size_t)bh * SEQ * HDIM;
  const short* vbase = vb + (size_t)bh * HDIM * SEQ;

  short8 qf[2][2];
#pragma unroll
  for (int rb = 0; rb < 2; ++rb) {
    const short* qrow = qb + ((size_t)bh * SEQ + qw0 + rb * 16 + lrow) * HDIM;
    qf[rb][0] = *(const short8*)(qrow + lkg * 8);
    qf[rb][1] = *(const short8*)(qrow + 32 + lkg * 8);
  }

  f32x4 o[2][4];
  float mr[2], lsum[2];
#pragma unroll
  for (int rb = 0; rb < 2; ++rb) {
#pragma unroll
    for (int g = 0; g < 4; ++g) o[rb][g] = (f32x4){0.f, 0.f, 0.f, 0.f};
    mr[rb] = -__builtin_inff();
    lsum[rb] = 0.f;
  }

  const int ntile = 32 - ip;  // covers heavy tile's causal range (superset of light's)

  for (int it = 0; it < ntile; ++it) {
    const int kt = it * 64;
    __syncthreads();  // all waves done reading previous tile
    // stage K tile (64x64 shorts) + V^T tile (64 dims x 64 tok), 256 threads x 4 loads
#pragma unroll
    for (int i = 0; i < 2; ++i)
      gload16(kbase + (size_t)kt * HDIM + i * 2048 + tid * 8, Ks + i * 2048 + tid * 8);
#pragma unroll
    for (int i = 0; i < 2; ++i)
      gload16(vbase + (size_t)(32 * i + (tid >> 3)) * SEQ + kt + (tid & 7) * 8,
              Vs + i * 2048 + tid * 8);
    __syncthreads();  // staged (vmcnt drained by barrier semantics)

    if (kt <= qw0 + 31) {  // wave-uniform: light waves skip past their diagonal
      // QK^T swapped: s[rb][f][r] = S[q = qw0+rb*16+lrow][k = kt+f*16+lkg*4+r]
      f32x4 s[2][4];
#pragma unroll
      for (int rb = 0; rb < 2; ++rb)
#pragma unroll
        for (int f = 0; f < 4; ++f) s[rb][f] = (f32x4){0.f, 0.f, 0.f, 0.f};

      __builtin_amdgcn_s_setprio(1);
#pragma unroll
      for (int c = 0; c < 2; ++c) {
#pragma unroll
        for (int f = 0; f < 4; ++f) {
          const int krow = f * 16 + lrow;
          const int kel = (c * 32 + lkg * 8) ^ ((krow & 7) << 3);
          short8 kf = *(const short8*)(Ks + krow * 64 + kel);
          s[0][f] = __builtin_amdgcn_mfma_f32_16x16x32_bf16(kf, qf[0][c], s[0][f], 0, 0, 0);
          s[1][f] = __builtin_amdgcn_mfma_f32_16x16x32_bf16(kf, qf[1][c], s[1][f], 0, 0, 0);
        }
      }
      __builtin_amdgcn_s_setprio(0);

      if (kt + 63 > qw0) {  // diagonal region: causal mask (k > q -> -inf)
#pragma unroll
        for (int rb = 0; rb < 2; ++rb) {
          const int qq = qw0 + rb * 16 + lrow;
#pragma unroll
          for (int f = 0; f < 4; ++f) {
            const int kg = kt + f * 16 + lkg * 4;
#pragma unroll
            for (int r = 0; r < 4; ++r)
              if (kg + r > qq) s[rb][f][r] = -__builtin_inff();
          }
        }
      }

      const float L2E = 1.44269504088896340736f;
      float pm[2];
#pragma unroll
      for (int rb = 0; rb < 2; ++rb) {
        float p = fmaxf(fmaxf(fmaxf(s[rb][0][0], s[rb][0][1]), fmaxf(s[rb][0][2], s[rb][0][3])),
                        fmaxf(fmaxf(s[rb][1][0], s[rb][1][1]), fmaxf(s[rb][1][2], s[rb][1][3])));
        p = fmaxf(p, fmaxf(fmaxf(fmaxf(s[rb][2][0], s[rb][2][1]), fmaxf(s[rb][2][2], s[rb][2][3])),
                           fmaxf(fmaxf(s[rb][3][0], s[rb][3][1]), fmaxf(s[rb][3][2], s[rb][3][3]))));
        p = fmaxf(p, __shfl_xor(p, 16));
        p = fmaxf(p, __shfl_xor(p, 32));
        pm[rb] = p;
      }
      const float mn0 = fmaxf(mr[0], pm[0]);
      const float mn1 = fmaxf(mr[1], pm[1]);
      // exact skip: if no row's max grew, every alpha == 1 -> no rescale needed
      if (!__all(pm[0] <= mr[0] && pm[1] <= mr[1])) {
        const float a0 = fast_exp2((mr[0] - mn0) * L2E);
        const float a1 = fast_exp2((mr[1] - mn1) * L2E);
        lsum[0] *= a0;
        lsum[1] *= a1;
#pragma unroll
        for (int r = 0; r < 4; ++r) {
          const float s0 = __shfl(a0, lkg * 4 + r, 16);
          const float s1 = __shfl(a1, lkg * 4 + r, 16);
#pragma unroll
          for (int g = 0; g < 4; ++g) { o[0][g][r] *= s0; o[1][g][r] *= s1; }
        }
      }
      mr[0] = mn0; mr[1] = mn1;

      unsigned int q32[2][4][2];
#pragma unroll
      for (int rb = 0; rb < 2; ++rb) {
        const float mn = rb ? mn1 : mn0;
        float rs = 0.f;
#pragma unroll
        for (int f = 0; f < 4; ++f)
#pragma unroll
          for (int r = 0; r < 4; ++r) {
            const float p = fast_exp2((s[rb][f][r] - mn) * L2E);
            s[rb][f][r] = p;
            rs += p;
          }
        rs += __shfl_xor(rs, 16);
        rs += __shfl_xor(rs, 32);
        lsum[rb] += rs;
#pragma unroll
        for (int f = 0; f < 4; ++f) {
          q32[rb][f][0] = pack_bf16(s[rb][f][0], s[rb][f][1]);
          q32[rb][f][1] = pack_bf16(s[rb][f][2], s[rb][f][3]);
        }
      }

      // O += P*V ; P A-frags assembled in-register via permlane swaps
      __builtin_amdgcn_s_setprio(1);
#pragma unroll
      for (int c = 0; c < 2; ++c) {
        uint4v pw0, pw1;
#pragma unroll
        for (int h = 0; h < 2; ++h) {
          unsigned int a0 = q32[0][2 * c][h], b0 = q32[0][2 * c + 1][h];
          permlane32_swap(a0, b0);
          permlane16_swap(a0, b0);
          pw0[h] = a0; pw0[2 + h] = b0;
          unsigned int a1 = q32[1][2 * c][h], b1 = q32[1][2 * c + 1][h];
          permlane32_swap(a1, b1);
          permlane16_swap(a1, b1);
          pw1[h] = a1; pw1[2 + h] = b1;
        }
        const short8 pf0 = __builtin_bit_cast(short8, pw0);
        const short8 pf1 = __builtin_bit_cast(short8, pw1);
#pragma unroll
        for (int g = 0; g < 4; ++g) {
          const int vrow = g * 16 + lrow;
          const int vel = (c * 32 + lkg * 8) ^ ((vrow & 7) << 3);
          short8 vf = *(const short8*)(Vs + vrow * 64 + vel);
          o[0][g] = __builtin_amdgcn_mfma_f32_16x16x32_bf16(pf0, vf, o[0][g], 0, 0, 0);
          o[1][g] = __builtin_amdgcn_mfma_f32_16x16x32_bf16(pf1, vf, o[1][g], 0, 0, 0);
        }
      }
      __builtin_amdgcn_s_setprio(0);
    }
  }

  const int b = bh >> 4, h = bh & 15;
  const float li0 = 1.0f / lsum[0];
  const float li1 = 1.0f / lsum[1];
#pragma unroll
  for (int r = 0; r < 4; ++r) {
    const float i0 = __shfl(li0, lkg * 4 + r, 16);
    const float i1 = __shfl(li1, lkg * 4 + r, 16);
    const int t0 = qw0 + lkg * 4 + r;
#pragma unroll
    for (int g = 0; g < 4; ++g) {
      aout[((size_t)b * SEQ + t0) * DMODEL + h * 64 + g * 16 + lrow] = f2bf(o[0][g][r] * i0);
      aout[((size_t)b * SEQ + t0 + 16) * DMODEL + h * 64 + g * 16 + lrow] = f2bf(o[1][g][r] * i1);
    }
  }
}

extern "C" void kernel_launch(void* const* d_in, const int* in_sizes, int n_in,
                              void* d_out, int out_size, void* d_ws, size_t ws_size,
                              hipStream_t stream) {
  const float* x = (const float*)d_in[0];
  // d_in[1] = mask (causal tril) — hardcoded in attn kernel
  const float* Wqkv = (const float*)d_in[2];
  const float* bqkv = (const float*)d_in[3];
  const float* Wout = (const float*)d_in[4];
  const float* bout = (const float*)d_in[5];

  char* ws = (char*)d_ws;
  short* xb    = (short*)(ws + 0);         // 16,777,216 B
  short* wqkvT = (short*)(ws + 16777216);  //  6,291,456 B
  short* woutT = (short*)(ws + 23068672);  //  2,097,152 B
  short* qbuf  = (short*)(ws + 25165824);  // 16,777,216 B
  short* kbuf  = (short*)(ws + 41943040);  // 16,777,216 B (row-swizzled)
  short* vbuf  = (short*)(ws + 58720256);  // 16,777,216 B (V^T per head, swizzled)
  short* abuf  = (short*)(ws + 75497472);  // 16,777,216 B — total 92,274,688 B

  cast_x_kernel<<<(MROWS * DMODEL) / 4 / 256, 256, 0, stream>>>(x, xb, MROWS * DMODEL);
  transpose_cast_kernel<<<dim3(N3 / 32, DMODEL / 32), dim3(32, 8), 0, stream>>>(
      Wqkv, wqkvT, DMODEL, N3);
  transpose_cast_kernel<<<dim3(DMODEL / 32, DMODEL / 32), dim3(32, 8), 0, stream>>>(
      Wout, woutT, DMODEL, DMODEL);
  gemm128_kernel<0><<<dim3(N3 / 128, MROWS / 128), 256, 0, stream>>>(
      xb, wqkvT, bqkv, nullptr, qbuf, kbuf, vbuf, MROWS, N3, DMODEL);
  attn_kernel<<<dim3(16, BHCNT), 256, 0, stream>>>(qbuf, kbuf, vbuf, abuf);
  gemm128_kernel<1><<<dim3(DMODEL / 128, MROWS / 128), 256, 0, stream>>>(
      abuf, woutT, bout, (float*)d_out, nullptr, nullptr, nullptr, MROWS, DMODEL, DMODEL);
}

// Round 12
// 287.717 us; speedup vs baseline: 1.4277x; 1.0206x over previous
//
#include <hip/hip_runtime.h>
#include <hip/hip_bf16.h>
#include <cstdint>
#include <cstddef>

#define DMODEL 1024
#define NHEADS 16
#define HDIM 64
#define BATCH 4
#define SEQ 2048
#define MROWS (BATCH*SEQ)   // 8192
#define N3 (3*DMODEL)       // 3072
#define BHCNT (BATCH*NHEADS) // 64

typedef __attribute__((ext_vector_type(8))) short short8;
typedef __attribute__((ext_vector_type(4))) short short4v;
typedef __attribute__((ext_vector_type(4))) float f32x4;
typedef __attribute__((ext_vector_type(4))) unsigned int uint4v;

// round-to-nearest-even f32 -> bf16 (data has no NaN)
static __device__ __forceinline__ short f2bf(float f) {
  unsigned int u = __builtin_bit_cast(unsigned int, f);
  return (short)((u + 0x7fffu + ((u >> 16) & 1u)) >> 16);
}

// pack two f32 -> one u32 of 2 bf16 (lo, hi) via gfx950 v_cvt_pk_bf16_f32
static __device__ __forceinline__ unsigned int pack_bf16(float lo, float hi) {
  unsigned int r;
  asm("v_cvt_pk_bf16_f32 %0, %1, %2" : "=v"(r) : "v"(lo), "v"(hi));
  return r;
}

// gfx950 fragment-transform swaps
static __device__ __forceinline__ void permlane32_swap(unsigned int& a, unsigned int& b) {
  asm("v_permlane32_swap_b32 %0, %1" : "+v"(a), "+v"(b));
}
static __device__ __forceinline__ void permlane16_swap(unsigned int& a, unsigned int& b) {
  asm("v_permlane16_swap_b32 %0, %1" : "+v"(a), "+v"(b));
}

static __device__ __forceinline__ float fast_exp2(float x) {
#if __has_builtin(__builtin_amdgcn_exp2f)
  return __builtin_amdgcn_exp2f(x);
#else
  return exp2f(x);
#endif
}

static __device__ __forceinline__ void gload16(const void* g, void* l) {
  __builtin_amdgcn_global_load_lds(
      (const __attribute__((address_space(1))) unsigned int*)g,
      (__attribute__((address_space(3))) unsigned int*)l, 16, 0, 0);
}

__global__ __launch_bounds__(256) void cast_x_kernel(
    const float* __restrict__ in, short* __restrict__ out, int n) {
  int i = (blockIdx.x * 256 + threadIdx.x) * 4;
  if (i + 3 < n) {
    float4 v = *(const float4*)(in + i);
    short4v s;
    s[0] = f2bf(v.x); s[1] = f2bf(v.y); s[2] = f2bf(v.z); s[3] = f2bf(v.w);
    *(short4v*)(out + i) = s;
  }
}

// in [K][N] f32 row-major -> out [N][K] bf16 row-major
__global__ __launch_bounds__(256) void transpose_cast_kernel(
    const float* __restrict__ in, short* __restrict__ out, int K, int N) {
  __shared__ float tile[32][33];
  int n0 = blockIdx.x * 32, k0 = blockIdx.y * 32;
  int tx = threadIdx.x, ty = threadIdx.y;  // 32 x 8
#pragma unroll
  for (int i = 0; i < 4; ++i)
    tile[ty + i * 8][tx] = in[(size_t)(k0 + ty + i * 8) * N + (n0 + tx)];
  __syncthreads();
#pragma unroll
  for (int i = 0; i < 4; ++i)
    out[(size_t)(n0 + ty + i * 8) * K + (k0 + tx)] = f2bf(tile[tx][ty + i * 8]);
}

// C[M,N] = A[M,K](bf16) * Bt[N,K]^T(bf16) + bias. 128x128 tile, 4 waves (2x2 of 64x64).
// m97-verified structure + XCD-aware block swizzle. (frozen this round for a
// clean baseline measurement once attn drops out of the top slots)
// EPI 0: scatter q/k/v (q scaled 0.125; k,v XOR-swizzled; v transposed per head)
// EPI 1: fp32 output
template <int EPI>
__global__ __launch_bounds__(256, 2) void gemm128_kernel(
    const short* __restrict__ A, const short* __restrict__ Bt,
    const float* __restrict__ bias, float* __restrict__ foutp,
    short* __restrict__ q_out, short* __restrict__ k_out,
    short* __restrict__ v_out, int Mdim, int Ndim, int Kdim) {
  __shared__ __align__(16) short As[128 * 32];
  __shared__ __align__(16) short Bs[128 * 32];
  const int tid = threadIdx.x;
  const int lane = tid & 63;
  const int w = tid >> 6;
  const int wr = w >> 1, wc = w & 1;
  // XCD-aware swizzle (nwg % 8 == 0 for both grids)
  const int nwg = gridDim.x * gridDim.y;
  const int lin = blockIdx.y * gridDim.x + blockIdx.x;
  const int tile = (lin & 7) * (nwg >> 3) + (lin >> 3);
  const int row0 = (tile / gridDim.x) * 128;
  const int col0 = (tile % gridDim.x) * 128;
  const int lrow = lane & 15, lkg = lane >> 4;

  f32x4 acc[4][4];
#pragma unroll
  for (int i = 0; i < 4; ++i)
#pragma unroll
    for (int j = 0; j < 4; ++j) acc[i][j] = (f32x4){0.f, 0.f, 0.f, 0.f};

  const short* Ab = A + (size_t)row0 * Kdim;
  const short* Bb = Bt + (size_t)col0 * Kdim;
  const int sr = tid >> 2;
  const int sc = (tid & 3) * 8;

  for (int kt = 0; kt < Kdim; kt += 32) {
    gload16(Ab + (size_t)sr * Kdim + kt + sc, As + tid * 8);
    gload16(Ab + (size_t)(sr + 64) * Kdim + kt + sc, As + 2048 + tid * 8);
    gload16(Bb + (size_t)sr * Kdim + kt + sc, Bs + tid * 8);
    gload16(Bb + (size_t)(sr + 64) * Kdim + kt + sc, Bs + 2048 + tid * 8);
    __syncthreads();
    short8 af[4], bfr[4];
#pragma unroll
    for (int i = 0; i < 4; ++i)
      af[i] = *(const short8*)(As + (wr * 64 + i * 16 + lrow) * 32 + lkg * 8);
#pragma unroll
    for (int j = 0; j < 4; ++j)
      bfr[j] = *(const short8*)(Bs + (wc * 64 + j * 16 + lrow) * 32 + lkg * 8);
#pragma unroll
    for (int i = 0; i < 4; ++i)
#pragma unroll
      for (int j = 0; j < 4; ++j)
        acc[i][j] = __builtin_amdgcn_mfma_f32_16x16x32_bf16(af[i], bfr[j], acc[i][j], 0, 0, 0);
    __syncthreads();
  }

#pragma unroll
  for (int i = 0; i < 4; ++i) {
#pragma unroll
    for (int j = 0; j < 4; ++j) {
      const int gn = col0 + wc * 64 + j * 16 + lrow;
      const int gmb = row0 + wr * 64 + i * 16 + lkg * 4;  // +r<4 never crosses 2048
      float vr[4];
#pragma unroll
      for (int r = 0; r < 4; ++r) vr[r] = acc[i][j][r] + bias[gn];
      if (EPI == 0) {
        const int which = gn >> 10;
        const int hh = (gn >> 6) & 15;
        const int dd = gn & 63;
        const int b = gmb >> 11;
        const int tt0 = gmb & 2047;
        const size_t bh = (size_t)b * NHEADS + hh;
        if (which == 0) {
#pragma unroll
          for (int r = 0; r < 4; ++r)
            q_out[(bh * SEQ + tt0 + r) * HDIM + dd] = f2bf(vr[r] * 0.125f);
        } else if (which == 1) {
#pragma unroll
          for (int r = 0; r < 4; ++r)
            k_out[(bh * SEQ + tt0 + r) * HDIM + (dd ^ (((tt0 + r) & 7) << 3))] = f2bf(vr[r]);
        } else {
          // V^T: 4 consecutive tokens for fixed dim -> one 8B store
          short4v pk;
#pragma unroll
          for (int r = 0; r < 4; ++r) pk[r] = f2bf(vr[r]);
          *(short4v*)(v_out + (bh * HDIM + dd) * SEQ + (tt0 ^ ((dd & 7) << 3))) = pk;
        }
      } else {
#pragma unroll
        for (int r = 0; r < 4; ++r)
          foutp[(size_t)(gmb + r) * Ndim + gn] = vr[r];
      }
    }
  }
}

// causal flash attention, PAIRED q-tiles + double-buffered K/V prefetch.
// Block = 4 waves: waves 0-1 own heavy q-tile (31-ip), waves 2-3 light (ip);
// one shared KV sweep serves both. Prefetch t+1 into alt buffer BEFORE
// computing t; single barrier per iteration (R2/R5-verified pattern) hides
// staging latency under QK/softmax/PV. 32KB LDS, 4 blocks/CU.
__global__ __launch_bounds__(256, 4) void attn_kernel(
    const short* __restrict__ qb, const short* __restrict__ kb,
    const short* __restrict__ vb, short* __restrict__ aout) {
  __shared__ __align__(16) short Ks2[2][64 * 64];
  __shared__ __align__(16) short Vs2[2][64 * 64];
  const int tid = threadIdx.x;   // 0..255
  const int lane = tid & 63;
  const int w = tid >> 6;        // 0..3
  // XCD swizzle: 1024 blocks -> 128/XCD = 8 consecutive heads (K/V ~L2-resident)
  const int lin = blockIdx.y * gridDim.x + blockIdx.x;
  const int tile = ((lin & 7) << 7) + (lin >> 3);
  const int bh = tile >> 4;
  const int ip = tile & 15;            // pair index; ip=0 (heaviest) first
  const int heavy_q0 = (31 - ip) * 64;
  const int light_q0 = ip * 64;
  const int qw0 = (w < 2) ? heavy_q0 + w * 32 : light_q0 + (w - 2) * 32;
  const int lrow = lane & 15, lkg = lane >> 4;

  const short* kbase = kb + (size_t)bh * SEQ * HDIM;
  const short* vbase = vb + (size_t)bh * HDIM * SEQ;

  short8 qf[2][2];
#pragma unroll
  for (int rb = 0; rb < 2; ++rb) {
    const short* qrow = qb + ((size_t)bh * SEQ + qw0 + rb * 16 + lrow) * HDIM;
    qf[rb][0] = *(const short8*)(qrow + lkg * 8);
    qf[rb][1] = *(const short8*)(qrow + 32 + lkg * 8);
  }

  f32x4 o[2][4];
  float mr[2], lsum[2];
#pragma unroll
  for (int rb = 0; rb < 2; ++rb) {
#pragma unroll
    for (int g = 0; g < 4; ++g) o[rb][g] = (f32x4){0.f, 0.f, 0.f, 0.f};
    mr[rb] = -__builtin_inff();
    lsum[rb] = 0.f;
  }

  const int ntile = 32 - ip;  // heavy tile's causal range (superset of light's)

  {  // prologue: stage tile 0 -> buf 0
    short* Kd = Ks2[0]; short* Vd = Vs2[0];
#pragma unroll
    for (int i = 0; i < 2; ++i)
      gload16(kbase + i * 2048 + tid * 8, Kd + i * 2048 + tid * 8);
#pragma unroll
    for (int i = 0; i < 2; ++i)
      gload16(vbase + (size_t)(32 * i + (tid >> 3)) * SEQ + (tid & 7) * 8,
              Vd + i * 2048 + tid * 8);
  }
  __syncthreads();

  int cur = 0;
  for (int it = 0; it < ntile; ++it) {
    const int kt = it * 64;
    if (it + 1 < ntile) {  // prefetch next tile into alternate buffer
      const int k2 = kt + 64;
      short* Kd = Ks2[cur ^ 1]; short* Vd = Vs2[cur ^ 1];
#pragma unroll
      for (int i = 0; i < 2; ++i)
        gload16(kbase + (size_t)k2 * HDIM + i * 2048 + tid * 8, Kd + i * 2048 + tid * 8);
#pragma unroll
      for (int i = 0; i < 2; ++i)
        gload16(vbase + (size_t)(32 * i + (tid >> 3)) * SEQ + k2 + (tid & 7) * 8,
                Vd + i * 2048 + tid * 8);
    }
    if (kt <= qw0 + 31) {  // wave-uniform: light waves skip past their diagonal
      const short* Ks = Ks2[cur];
      const short* Vs = Vs2[cur];
      // QK^T swapped: s[rb][f][r] = S[q = qw0+rb*16+lrow][k = kt+f*16+lkg*4+r]
      f32x4 s[2][4];
#pragma unroll
      for (int rb = 0; rb < 2; ++rb)
#pragma unroll
        for (int f = 0; f < 4; ++f) s[rb][f] = (f32x4){0.f, 0.f, 0.f, 0.f};

      __builtin_amdgcn_s_setprio(1);
#pragma unroll
      for (int c = 0; c < 2; ++c) {
#pragma unroll
        for (int f = 0; f < 4; ++f) {
          const int krow = f * 16 + lrow;
          const int kel = (c * 32 + lkg * 8) ^ ((krow & 7) << 3);
          short8 kf = *(const short8*)(Ks + krow * 64 + kel);
          s[0][f] = __builtin_amdgcn_mfma_f32_16x16x32_bf16(kf, qf[0][c], s[0][f], 0, 0, 0);
          s[1][f] = __builtin_amdgcn_mfma_f32_16x16x32_bf16(kf, qf[1][c], s[1][f], 0, 0, 0);
        }
      }
      __builtin_amdgcn_s_setprio(0);

      if (kt + 63 > qw0) {  // diagonal region: causal mask (k > q -> -inf)
#pragma unroll
        for (int rb = 0; rb < 2; ++rb) {
          const int qq = qw0 + rb * 16 + lrow;
#pragma unroll
          for (int f = 0; f < 4; ++f) {
            const int kg = kt + f * 16 + lkg * 4;
#pragma unroll
            for (int r = 0; r < 4; ++r)
              if (kg + r > qq) s[rb][f][r] = -__builtin_inff();
          }
        }
      }

      const float L2E = 1.44269504088896340736f;
      float pm[2];
#pragma unroll
      for (int rb = 0; rb < 2; ++rb) {
        float p = fmaxf(fmaxf(fmaxf(s[rb][0][0], s[rb][0][1]), fmaxf(s[rb][0][2], s[rb][0][3])),
                        fmaxf(fmaxf(s[rb][1][0], s[rb][1][1]), fmaxf(s[rb][1][2], s[rb][1][3])));
        p = fmaxf(p, fmaxf(fmaxf(fmaxf(s[rb][2][0], s[rb][2][1]), fmaxf(s[rb][2][2], s[rb][2][3])),
                           fmaxf(fmaxf(s[rb][3][0], s[rb][3][1]), fmaxf(s[rb][3][2], s[rb][3][3]))));
        p = fmaxf(p, __shfl_xor(p, 16));
        p = fmaxf(p, __shfl_xor(p, 32));
        pm[rb] = p;
      }
      const float mn0 = fmaxf(mr[0], pm[0]);
      const float mn1 = fmaxf(mr[1], pm[1]);
      // exact skip: if no row's max grew, every alpha == 1 -> no rescale needed
      if (!__all(pm[0] <= mr[0] && pm[1] <= mr[1])) {
        const float a0 = fast_exp2((mr[0] - mn0) * L2E);
        const float a1 = fast_exp2((mr[1] - mn1) * L2E);
        lsum[0] *= a0;
        lsum[1] *= a1;
#pragma unroll
        for (int r = 0; r < 4; ++r) {
          const float s0 = __shfl(a0, lkg * 4 + r, 16);
          const float s1 = __shfl(a1, lkg * 4 + r, 16);
#pragma unroll
          for (int g = 0; g < 4; ++g) { o[0][g][r] *= s0; o[1][g][r] *= s1; }
        }
      }
      mr[0] = mn0; mr[1] = mn1;

      unsigned int q32[2][4][2];
#pragma unroll
      for (int rb = 0; rb < 2; ++rb) {
        const float mn = rb ? mn1 : mn0;
        float rs = 0.f;
#pragma unroll
        for (int f = 0; f < 4; ++f)
#pragma unroll
          for (int r = 0; r < 4; ++r) {
            const float p = fast_exp2((s[rb][f][r] - mn) * L2E);
            s[rb][f][r] = p;
            rs += p;
          }
        rs += __shfl_xor(rs, 16);
        rs += __shfl_xor(rs, 32);
        lsum[rb] += rs;
#pragma unroll
        for (int f = 0; f < 4; ++f) {
          q32[rb][f][0] = pack_bf16(s[rb][f][0], s[rb][f][1]);
          q32[rb][f][1] = pack_bf16(s[rb][f][2], s[rb][f][3]);
        }
      }

      // O += P*V ; P A-frags assembled in-register via permlane swaps
      __builtin_amdgcn_s_setprio(1);
#pragma unroll
      for (int c = 0; c < 2; ++c) {
        uint4v pw0, pw1;
#pragma unroll
        for (int h = 0; h < 2; ++h) {
          unsigned int a0 = q32[0][2 * c][h], b0 = q32[0][2 * c + 1][h];
          permlane32_swap(a0, b0);
          permlane16_swap(a0, b0);
          pw0[h] = a0; pw0[2 + h] = b0;
          unsigned int a1 = q32[1][2 * c][h], b1 = q32[1][2 * c + 1][h];
          permlane32_swap(a1, b1);
          permlane16_swap(a1, b1);
          pw1[h] = a1; pw1[2 + h] = b1;
        }
        const short8 pf0 = __builtin_bit_cast(short8, pw0);
        const short8 pf1 = __builtin_bit_cast(short8, pw1);
#pragma unroll
        for (int g = 0; g < 4; ++g) {
          const int vrow = g * 16 + lrow;
          const int vel = (c * 32 + lkg * 8) ^ ((vrow & 7) << 3);
          short8 vf = *(const short8*)(Vs + vrow * 64 + vel);
          o[0][g] = __builtin_amdgcn_mfma_f32_16x16x32_bf16(pf0, vf, o[0][g], 0, 0, 0);
          o[1][g] = __builtin_amdgcn_mfma_f32_16x16x32_bf16(pf1, vf, o[1][g], 0, 0, 0);
        }
      }
      __builtin_amdgcn_s_setprio(0);
    }
    __syncthreads();  // drains prefetch vmcnt; next iter reads alt buffer
    cur ^= 1;
  }

  const int b = bh >> 4, h = bh & 15;
  const float li0 = 1.0f / lsum[0];
  const float li1 = 1.0f / lsum[1];
#pragma unroll
  for (int r = 0; r < 4; ++r) {
    const float i0 = __shfl(li0, lkg * 4 + r, 16);
    const float i1 = __shfl(li1, lkg * 4 + r, 16);
    const int t0 = qw0 + lkg * 4 + r;
#pragma unroll
    for (int g = 0; g < 4; ++g) {
      aout[((size_t)b * SEQ + t0) * DMODEL + h * 64 + g * 16 + lrow] = f2bf(o[0][g][r] * i0);
      aout[((size_t)b * SEQ + t0 + 16) * DMODEL + h * 64 + g * 16 + lrow] = f2bf(o[1][g][r] * i1);
    }
  }
}

extern "C" void kernel_launch(void* const* d_in, const int* in_sizes, int n_in,
                              void* d_out, int out_size, void* d_ws, size_t ws_size,
                              hipStream_t stream) {
  const float* x = (const float*)d_in[0];
  // d_in[1] = mask (causal tril) — hardcoded in attn kernel
  const float* Wqkv = (const float*)d_in[2];
  const float* bqkv = (const float*)d_in[3];
  const float* Wout = (const float*)d_in[4];
  const float* bout = (const float*)d_in[5];

  char* ws = (char*)d_ws;
  short* xb    = (short*)(ws + 0);         // 16,777,216 B
  short* wqkvT = (short*)(ws + 16777216);  //  6,291,456 B
  short* woutT = (short*)(ws + 23068672);  //  2,097,152 B
  short* qbuf  = (short*)(ws + 25165824);  // 16,777,216 B
  short* kbuf  = (short*)(ws + 41943040);  // 16,777,216 B (row-swizzled)
  short* vbuf  = (short*)(ws + 58720256);  // 16,777,216 B (V^T per head, swizzled)
  short* abuf  = (short*)(ws + 75497472);  // 16,777,216 B — total 92,274,688 B

  cast_x_kernel<<<(MROWS * DMODEL) / 4 / 256, 256, 0, stream>>>(x, xb, MROWS * DMODEL);
  transpose_cast_kernel<<<dim3(N3 / 32, DMODEL / 32), dim3(32, 8), 0, stream>>>(
      Wqkv, wqkvT, DMODEL, N3);
  transpose_cast_kernel<<<dim3(DMODEL / 32, DMODEL / 32), dim3(32, 8), 0, stream>>>(
      Wout, woutT, DMODEL, DMODEL);
  gemm128_kernel<0><<<dim3(N3 / 128, MROWS / 128), 256, 0, stream>>>(
      xb, wqkvT, bqkv, nullptr, qbuf, kbuf, vbuf, MROWS, N3, DMODEL);
  attn_kernel<<<dim3(16, BHCNT), 256, 0, stream>>>(qbuf, kbuf, vbuf, abuf);
  gemm128_kernel<1><<<dim3(DMODEL / 128, MROWS / 128), 256, 0, stream>>>(
      abuf, woutT, bout, (float*)d_out, nullptr, nullptr, nullptr, MROWS, DMODEL, DMODEL);
}

// Round 13
// 273.838 us; speedup vs baseline: 1.5000x; 1.0507x over previous
//
#include <hip/hip_runtime.h>
#include <hip/hip_bf16.h>
#include <cstdint>
#include <cstddef>

#define DMODEL 1024
#define NHEADS 16
#define HDIM 64
#define BATCH 4
#define SEQ 2048
#define MROWS (BATCH*SEQ)   // 8192
#define N3 (3*DMODEL)       // 3072
#define BHCNT (BATCH*NHEADS) // 64

typedef __attribute__((ext_vector_type(8))) short short8;
typedef __attribute__((ext_vector_type(4))) short short4v;
typedef __attribute__((ext_vector_type(4))) float f32x4;
typedef __attribute__((ext_vector_type(4))) unsigned int uint4v;

// round-to-nearest-even f32 -> bf16 (data has no NaN)
static __device__ __forceinline__ short f2bf(float f) {
  unsigned int u = __builtin_bit_cast(unsigned int, f);
  return (short)((u + 0x7fffu + ((u >> 16) & 1u)) >> 16);
}

// pack two f32 -> one u32 of 2 bf16 (lo, hi) via gfx950 v_cvt_pk_bf16_f32
static __device__ __forceinline__ unsigned int pack_bf16(float lo, float hi) {
  unsigned int r;
  asm("v_cvt_pk_bf16_f32 %0, %1, %2" : "=v"(r) : "v"(lo), "v"(hi));
  return r;
}

// gfx950 fragment-transform swaps
static __device__ __forceinline__ void permlane32_swap(unsigned int& a, unsigned int& b) {
  asm("v_permlane32_swap_b32 %0, %1" : "+v"(a), "+v"(b));
}
static __device__ __forceinline__ void permlane16_swap(unsigned int& a, unsigned int& b) {
  asm("v_permlane16_swap_b32 %0, %1" : "+v"(a), "+v"(b));
}

static __device__ __forceinline__ float fast_exp2(float x) {
#if __has_builtin(__builtin_amdgcn_exp2f)
  return __builtin_amdgcn_exp2f(x);
#else
  return exp2f(x);
#endif
}

static __device__ __forceinline__ void gload16(const void* g, void* l) {
  __builtin_amdgcn_global_load_lds(
      (const __attribute__((address_space(1))) unsigned int*)g,
      (__attribute__((address_space(3))) unsigned int*)l, 16, 0, 0);
}

__global__ __launch_bounds__(256) void cast_x_kernel(
    const float* __restrict__ in, short* __restrict__ out, int n) {
  int i = (blockIdx.x * 256 + threadIdx.x) * 4;
  if (i + 3 < n) {
    float4 v = *(const float4*)(in + i);
    short4v s;
    s[0] = f2bf(v.x); s[1] = f2bf(v.y); s[2] = f2bf(v.z); s[3] = f2bf(v.w);
    *(short4v*)(out + i) = s;
  }
}

// in [K][N] f32 row-major -> out [N][K] bf16 row-major
__global__ __launch_bounds__(256) void transpose_cast_kernel(
    const float* __restrict__ in, short* __restrict__ out, int K, int N) {
  __shared__ float tile[32][33];
  int n0 = blockIdx.x * 32, k0 = blockIdx.y * 32;
  int tx = threadIdx.x, ty = threadIdx.y;  // 32 x 8
#pragma unroll
  for (int i = 0; i < 4; ++i)
    tile[ty + i * 8][tx] = in[(size_t)(k0 + ty + i * 8) * N + (n0 + tx)];
  __syncthreads();
#pragma unroll
  for (int i = 0; i < 4; ++i)
    out[(size_t)(n0 + ty + i * 8) * K + (k0 + tx)] = f2bf(tile[tx][ty + i * 8]);
}

// C[M,N] = A[M,K](bf16) * Bt[N,K]^T(bf16) + bias. 128x128 tile, 4 waves (2x2 of 64x64).
// m97-verified structure + XCD-aware block swizzle. (frozen)
template <int EPI>
__global__ __launch_bounds__(256, 2) void gemm128_kernel(
    const short* __restrict__ A, const short* __restrict__ Bt,
    const float* __restrict__ bias, float* __restrict__ foutp,
    short* __restrict__ q_out, short* __restrict__ k_out,
    short* __restrict__ v_out, int Mdim, int Ndim, int Kdim) {
  __shared__ __align__(16) short As[128 * 32];
  __shared__ __align__(16) short Bs[128 * 32];
  const int tid = threadIdx.x;
  const int lane = tid & 63;
  const int w = tid >> 6;
  const int wr = w >> 1, wc = w & 1;
  const int nwg = gridDim.x * gridDim.y;
  const int lin = blockIdx.y * gridDim.x + blockIdx.x;
  const int tile = (lin & 7) * (nwg >> 3) + (lin >> 3);
  const int row0 = (tile / gridDim.x) * 128;
  const int col0 = (tile % gridDim.x) * 128;
  const int lrow = lane & 15, lkg = lane >> 4;

  f32x4 acc[4][4];
#pragma unroll
  for (int i = 0; i < 4; ++i)
#pragma unroll
    for (int j = 0; j < 4; ++j) acc[i][j] = (f32x4){0.f, 0.f, 0.f, 0.f};

  const short* Ab = A + (size_t)row0 * Kdim;
  const short* Bb = Bt + (size_t)col0 * Kdim;
  const int sr = tid >> 2;
  const int sc = (tid & 3) * 8;

  for (int kt = 0; kt < Kdim; kt += 32) {
    gload16(Ab + (size_t)sr * Kdim + kt + sc, As + tid * 8);
    gload16(Ab + (size_t)(sr + 64) * Kdim + kt + sc, As + 2048 + tid * 8);
    gload16(Bb + (size_t)sr * Kdim + kt + sc, Bs + tid * 8);
    gload16(Bb + (size_t)(sr + 64) * Kdim + kt + sc, Bs + 2048 + tid * 8);
    __syncthreads();
    short8 af[4], bfr[4];
#pragma unroll
    for (int i = 0; i < 4; ++i)
      af[i] = *(const short8*)(As + (wr * 64 + i * 16 + lrow) * 32 + lkg * 8);
#pragma unroll
    for (int j = 0; j < 4; ++j)
      bfr[j] = *(const short8*)(Bs + (wc * 64 + j * 16 + lrow) * 32 + lkg * 8);
#pragma unroll
    for (int i = 0; i < 4; ++i)
#pragma unroll
      for (int j = 0; j < 4; ++j)
        acc[i][j] = __builtin_amdgcn_mfma_f32_16x16x32_bf16(af[i], bfr[j], acc[i][j], 0, 0, 0);
    __syncthreads();
  }

#pragma unroll
  for (int i = 0; i < 4; ++i) {
#pragma unroll
    for (int j = 0; j < 4; ++j) {
      const int gn = col0 + wc * 64 + j * 16 + lrow;
      const int gmb = row0 + wr * 64 + i * 16 + lkg * 4;  // +r<4 never crosses 2048
      float vr[4];
#pragma unroll
      for (int r = 0; r < 4; ++r) vr[r] = acc[i][j][r] + bias[gn];
      if (EPI == 0) {
        const int which = gn >> 10;
        const int hh = (gn >> 6) & 15;
        const int dd = gn & 63;
        const int b = gmb >> 11;
        const int tt0 = gmb & 2047;
        const size_t bh = (size_t)b * NHEADS + hh;
        if (which == 0) {
#pragma unroll
          for (int r = 0; r < 4; ++r)
            q_out[(bh * SEQ + tt0 + r) * HDIM + dd] = f2bf(vr[r] * 0.125f);
        } else if (which == 1) {
#pragma unroll
          for (int r = 0; r < 4; ++r)
            k_out[(bh * SEQ + tt0 + r) * HDIM + (dd ^ (((tt0 + r) & 7) << 3))] = f2bf(vr[r]);
        } else {
          short4v pk;
#pragma unroll
          for (int r = 0; r < 4; ++r) pk[r] = f2bf(vr[r]);
          *(short4v*)(v_out + (bh * HDIM + dd) * SEQ + (tt0 ^ ((dd & 7) << 3))) = pk;
        }
      } else {
#pragma unroll
        for (int r = 0; r < 4; ++r)
          foutp[(size_t)(gmb + r) * Ndim + gn] = vr[r];
      }
    }
  }
}

// One 16-q-row group vs one 64-KV tile: swapped QK^T, in-register softmax
// (tree reductions), exact rescale-skip, permlane P-relayout, PV accumulate.
static __device__ __forceinline__ void attn_rb_tile(
    const short* __restrict__ Ks, const short* __restrict__ Vs,
    const short8 qf[2], f32x4 o[4], float& mr, float& lsum,
    bool diag, int kt, int qq, int lrow, int lkg) {
  f32x4 s[4];
#pragma unroll
  for (int f = 0; f < 4; ++f) s[f] = (f32x4){0.f, 0.f, 0.f, 0.f};

  __builtin_amdgcn_s_setprio(1);
#pragma unroll
  for (int c = 0; c < 2; ++c) {
#pragma unroll
    for (int f = 0; f < 4; ++f) {
      const int krow = f * 16 + lrow;
      const int kel = (c * 32 + lkg * 8) ^ ((krow & 7) << 3);
      short8 kf = *(const short8*)(Ks + krow * 64 + kel);
      s[f] = __builtin_amdgcn_mfma_f32_16x16x32_bf16(kf, qf[c], s[f], 0, 0, 0);
    }
  }
  __builtin_amdgcn_s_setprio(0);

  if (diag) {
#pragma unroll
    for (int f = 0; f < 4; ++f) {
      const int kg = kt + f * 16 + lkg * 4;
#pragma unroll
      for (int r = 0; r < 4; ++r)
        if (kg + r > qq) s[f][r] = -__builtin_inff();
    }
  }

  const float L2E = 1.44269504088896340736f;
  float pm = fmaxf(fmaxf(fmaxf(s[0][0], s[0][1]), fmaxf(s[0][2], s[0][3])),
                   fmaxf(fmaxf(s[1][0], s[1][1]), fmaxf(s[1][2], s[1][3])));
  pm = fmaxf(pm, fmaxf(fmaxf(fmaxf(s[2][0], s[2][1]), fmaxf(s[2][2], s[2][3])),
                       fmaxf(fmaxf(s[3][0], s[3][1]), fmaxf(s[3][2], s[3][3]))));
  pm = fmaxf(pm, __shfl_xor(pm, 16));
  pm = fmaxf(pm, __shfl_xor(pm, 32));
  const float mn = fmaxf(mr, pm);
  // exact skip: alpha==1 for every row -> no rescale
  if (!__all(pm <= mr)) {
    const float a = fast_exp2((mr - mn) * L2E);
    lsum *= a;
#pragma unroll
    for (int r = 0; r < 4; ++r) {
      const float ar = __shfl(a, lkg * 4 + r, 16);
#pragma unroll
      for (int g = 0; g < 4; ++g) o[g][r] *= ar;
    }
  }
  mr = mn;

  float rf[4];
#pragma unroll
  for (int f = 0; f < 4; ++f) {
#pragma unroll
    for (int r = 0; r < 4; ++r) s[f][r] = fast_exp2((s[f][r] - mn) * L2E);
    rf[f] = (s[f][0] + s[f][1]) + (s[f][2] + s[f][3]);  // tree
  }
  float rs = (rf[0] + rf[1]) + (rf[2] + rf[3]);
  rs += __shfl_xor(rs, 16);
  rs += __shfl_xor(rs, 32);
  lsum += rs;

  unsigned int q32[4][2];
#pragma unroll
  for (int f = 0; f < 4; ++f) {
    q32[f][0] = pack_bf16(s[f][0], s[f][1]);
    q32[f][1] = pack_bf16(s[f][2], s[f][3]);
  }

  __builtin_amdgcn_s_setprio(1);
#pragma unroll
  for (int c = 0; c < 2; ++c) {
    uint4v pw;
#pragma unroll
    for (int h = 0; h < 2; ++h) {
      unsigned int a = q32[2 * c][h], b = q32[2 * c + 1][h];
      permlane32_swap(a, b);
      permlane16_swap(a, b);
      pw[h] = a; pw[2 + h] = b;
    }
    const short8 pf = __builtin_bit_cast(short8, pw);
#pragma unroll
    for (int g = 0; g < 4; ++g) {
      const int vrow = g * 16 + lrow;
      const int vel = (c * 32 + lkg * 8) ^ ((vrow & 7) << 3);
      short8 vf = *(const short8*)(Vs + vrow * 64 + vel);
      o[g] = __builtin_amdgcn_mfma_f32_16x16x32_bf16(pf, vf, o[g], 0, 0, 0);
    }
  }
  __builtin_amdgcn_s_setprio(0);
}

// causal flash attention, ROW-SPLIT paired q-tiles: every wave owns 16 heavy
// rows (rb0, tile 31-ip) + 16 light rows (rb1, tile ip). Both tiles are
// 64-aligned to KV tiles, so rb1 is active exactly for it<=ip (block-uniform)
// -> zero wave idling; block cost = 33 units constant across all pairs
// (was 34..64). Shared KV sweep, double-buffered staging, 32KB LDS.
__global__ __launch_bounds__(256, 4) void attn_kernel(
    const short* __restrict__ qb, const short* __restrict__ kb,
    const short* __restrict__ vb, short* __restrict__ aout) {
  __shared__ __align__(16) short Ks2[2][64 * 64];
  __shared__ __align__(16) short Vs2[2][64 * 64];
  const int tid = threadIdx.x;   // 0..255
  const int lane = tid & 63;
  const int w = tid >> 6;        // 0..3
  // XCD swizzle: 1024 blocks -> 128/XCD = 8 consecutive heads (K/V ~L2-resident)
  const int lin = blockIdx.y * gridDim.x + blockIdx.x;
  const int tile = ((lin & 7) << 7) + (lin >> 3);
  const int bh = tile >> 4;
  const int ip = tile & 15;            // pair index
  const int heavy_q0 = (31 - ip) * 64;
  const int light_q0 = ip * 64;
  const int qr0 = heavy_q0 + w * 16;   // this wave's 16 heavy rows
  const int qr1 = light_q0 + w * 16;   // this wave's 16 light rows
  const int lrow = lane & 15, lkg = lane >> 4;

  const short* kbase = kb + (size_t)bh * SEQ * HDIM;
  const short* vbase = vb + (size_t)bh * HDIM * SEQ;

  short8 qf0[2], qf1[2];
  {
    const short* qrow = qb + ((size_t)bh * SEQ + qr0 + lrow) * HDIM;
    qf0[0] = *(const short8*)(qrow + lkg * 8);
    qf0[1] = *(const short8*)(qrow + 32 + lkg * 8);
    const short* qrow1 = qb + ((size_t)bh * SEQ + qr1 + lrow) * HDIM;
    qf1[0] = *(const short8*)(qrow1 + lkg * 8);
    qf1[1] = *(const short8*)(qrow1 + 32 + lkg * 8);
  }

  f32x4 o0[4], o1[4];
  float mr0 = -__builtin_inff(), mr1 = -__builtin_inff();
  float ls0 = 0.f, ls1 = 0.f;
#pragma unroll
  for (int g = 0; g < 4; ++g) {
    o0[g] = (f32x4){0.f, 0.f, 0.f, 0.f};
    o1[g] = (f32x4){0.f, 0.f, 0.f, 0.f};
  }

  const int ntile = 32 - ip;  // heavy range (superset of light's prefix)

  {  // prologue: stage tile 0 -> buf 0
    short* Kd = Ks2[0]; short* Vd = Vs2[0];
#pragma unroll
    for (int i = 0; i < 2; ++i)
      gload16(kbase + i * 2048 + tid * 8, Kd + i * 2048 + tid * 8);
#pragma unroll
    for (int i = 0; i < 2; ++i)
      gload16(vbase + (size_t)(32 * i + (tid >> 3)) * SEQ + (tid & 7) * 8,
              Vd + i * 2048 + tid * 8);
  }
  __syncthreads();

  int cur = 0;
  for (int it = 0; it < ntile; ++it) {
    const int kt = it * 64;
    if (it + 1 < ntile) {  // prefetch next tile into alternate buffer
      const int k2 = kt + 64;
      short* Kd = Ks2[cur ^ 1]; short* Vd = Vs2[cur ^ 1];
#pragma unroll
      for (int i = 0; i < 2; ++i)
        gload16(kbase + (size_t)k2 * HDIM + i * 2048 + tid * 8, Kd + i * 2048 + tid * 8);
#pragma unroll
      for (int i = 0; i < 2; ++i)
        gload16(vbase + (size_t)(32 * i + (tid >> 3)) * SEQ + k2 + (tid & 7) * 8,
                Vd + i * 2048 + tid * 8);
    }
    const short* Ks = Ks2[cur];
    const short* Vs = Vs2[cur];
    // rb0 (heavy): active every iteration; diag only on the last tile
    attn_rb_tile(Ks, Vs, qf0, o0, mr0, ls0,
                 kt + 63 > qr0, kt, qr0 + lrow, lrow, lkg);
    // rb1 (light): active for it <= ip (block-uniform; tiles 64-aligned)
    if (it <= ip)
      attn_rb_tile(Ks, Vs, qf1, o1, mr1, ls1,
                   kt + 63 > qr1, kt, qr1 + lrow, lrow, lkg);
    __syncthreads();  // drains prefetch; next iter reads alt buffer
    cur ^= 1;
  }

  const int b = bh >> 4, h = bh & 15;
  const float li0 = 1.0f / ls0;
  const float li1 = 1.0f / ls1;
#pragma unroll
  for (int r = 0; r < 4; ++r) {
    const float i0 = __shfl(li0, lkg * 4 + r, 16);
    const float i1 = __shfl(li1, lkg * 4 + r, 16);
    const int t0 = qr0 + lkg * 4 + r;
    const int t1 = qr1 + lkg * 4 + r;
#pragma unroll
    for (int g = 0; g < 4; ++g) {
      aout[((size_t)b * SEQ + t0) * DMODEL + h * 64 + g * 16 + lrow] = f2bf(o0[g][r] * i0);
      aout[((size_t)b * SEQ + t1) * DMODEL + h * 64 + g * 16 + lrow] = f2bf(o1[g][r] * i1);
    }
  }
}

extern "C" void kernel_launch(void* const* d_in, const int* in_sizes, int n_in,
                              void* d_out, int out_size, void* d_ws, size_t ws_size,
                              hipStream_t stream) {
  const float* x = (const float*)d_in[0];
  // d_in[1] = mask (causal tril) — hardcoded in attn kernel
  const float* Wqkv = (const float*)d_in[2];
  const float* bqkv = (const float*)d_in[3];
  const float* Wout = (const float*)d_in[4];
  const float* bout = (const float*)d_in[5];

  char* ws = (char*)d_ws;
  short* xb    = (short*)(ws + 0);         // 16,777,216 B
  short* wqkvT = (short*)(ws + 16777216);  //  6,291,456 B
  short* woutT = (short*)(ws + 23068672);  //  2,097,152 B
  short* qbuf  = (short*)(ws + 25165824);  // 16,777,216 B
  short* kbuf  = (short*)(ws + 41943040);  // 16,777,216 B (row-swizzled)
  short* vbuf  = (short*)(ws + 58720256);  // 16,777,216 B (V^T per head, swizzled)
  short* abuf  = (short*)(ws + 75497472);  // 16,777,216 B — total 92,274,688 B

  cast_x_kernel<<<(MROWS * DMODEL) / 4 / 256, 256, 0, stream>>>(x, xb, MROWS * DMODEL);
  transpose_cast_kernel<<<dim3(N3 / 32, DMODEL / 32), dim3(32, 8), 0, stream>>>(
      Wqkv, wqkvT, DMODEL, N3);
  transpose_cast_kernel<<<dim3(DMODEL / 32, DMODEL / 32), dim3(32, 8), 0, stream>>>(
      Wout, woutT, DMODEL, DMODEL);
  gemm128_kernel<0><<<dim3(N3 / 128, MROWS / 128), 256, 0, stream>>>(
      xb, wqkvT, bqkv, nullptr, qbuf, kbuf, vbuf, MROWS, N3, DMODEL);
  attn_kernel<<<dim3(16, BHCNT), 256, 0, stream>>>(qbuf, kbuf, vbuf, abuf);
  gemm128_kernel<1><<<dim3(DMODEL / 128, MROWS / 128), 256, 0, stream>>>(
      abuf, woutT, bout, (float*)d_out, nullptr, nullptr, nullptr, MROWS, DMODEL, DMODEL);
}

// Round 14
// 273.567 us; speedup vs baseline: 1.5015x; 1.0010x over previous
//
#include <hip/hip_runtime.h>
#include <hip/hip_bf16.h>
#include <cstdint>
#include <cstddef>

#define DMODEL 1024
#define NHEADS 16
#define HDIM 64
#define BATCH 4
#define SEQ 2048
#define MROWS (BATCH*SEQ)   // 8192
#define N3 (3*DMODEL)       // 3072
#define BHCNT (BATCH*NHEADS) // 64

typedef __attribute__((ext_vector_type(8))) short short8;
typedef __attribute__((ext_vector_type(4))) short short4v;
typedef __attribute__((ext_vector_type(4))) float f32x4;
typedef __attribute__((ext_vector_type(4))) unsigned int uint4v;

// round-to-nearest-even f32 -> bf16 (data has no NaN)
static __device__ __forceinline__ short f2bf(float f) {
  unsigned int u = __builtin_bit_cast(unsigned int, f);
  return (short)((u + 0x7fffu + ((u >> 16) & 1u)) >> 16);
}

// pack two f32 -> one u32 of 2 bf16 (lo, hi) via gfx950 v_cvt_pk_bf16_f32
static __device__ __forceinline__ unsigned int pack_bf16(float lo, float hi) {
  unsigned int r;
  asm("v_cvt_pk_bf16_f32 %0, %1, %2" : "=v"(r) : "v"(lo), "v"(hi));
  return r;
}

// gfx950 fragment-transform swaps
static __device__ __forceinline__ void permlane32_swap(unsigned int& a, unsigned int& b) {
  asm("v_permlane32_swap_b32 %0, %1" : "+v"(a), "+v"(b));
}
static __device__ __forceinline__ void permlane16_swap(unsigned int& a, unsigned int& b) {
  asm("v_permlane16_swap_b32 %0, %1" : "+v"(a), "+v"(b));
}

static __device__ __forceinline__ float fast_exp2(float x) {
#if __has_builtin(__builtin_amdgcn_exp2f)
  return __builtin_amdgcn_exp2f(x);
#else
  return exp2f(x);
#endif
}

static __device__ __forceinline__ void gload16(const void* g, void* l) {
  __builtin_amdgcn_global_load_lds(
      (const __attribute__((address_space(1))) unsigned int*)g,
      (__attribute__((address_space(3))) unsigned int*)l, 16, 0, 0);
}

__global__ __launch_bounds__(256) void cast_x_kernel(
    const float* __restrict__ in, short* __restrict__ out, int n) {
  int i = (blockIdx.x * 256 + threadIdx.x) * 4;
  if (i + 3 < n) {
    float4 v = *(const float4*)(in + i);
    short4v s;
    s[0] = f2bf(v.x); s[1] = f2bf(v.y); s[2] = f2bf(v.z); s[3] = f2bf(v.w);
    *(short4v*)(out + i) = s;
  }
}

// in [K][N] f32 row-major -> out [N][K] bf16 row-major
__global__ __launch_bounds__(256) void transpose_cast_kernel(
    const float* __restrict__ in, short* __restrict__ out, int K, int N) {
  __shared__ float tile[32][33];
  int n0 = blockIdx.x * 32, k0 = blockIdx.y * 32;
  int tx = threadIdx.x, ty = threadIdx.y;  // 32 x 8
#pragma unroll
  for (int i = 0; i < 4; ++i)
    tile[ty + i * 8][tx] = in[(size_t)(k0 + ty + i * 8) * N + (n0 + tx)];
  __syncthreads();
#pragma unroll
  for (int i = 0; i < 4; ++i)
    out[(size_t)(n0 + ty + i * 8) * K + (k0 + tx)] = f2bf(tile[tx][ty + i * 8]);
}

// C[M,N] = A[M,K](bf16) * Bt[N,K]^T(bf16) + bias. 128x128 tile, 4 waves (2x2 of 64x64).
// m97-verified structure + XCD-aware block swizzle. (frozen — 616 TF on gemm1)
// EPI 0: scatter q/k/v; EPI 1: fp32 output
template <int EPI>
__global__ __launch_bounds__(256, 2) void gemm128_kernel(
    const short* __restrict__ A, const short* __restrict__ Bt,
    const float* __restrict__ bias, float* __restrict__ foutp,
    short* __restrict__ q_out, short* __restrict__ k_out,
    short* __restrict__ v_out, int Mdim, int Ndim, int Kdim) {
  __shared__ __align__(16) short As[128 * 32];
  __shared__ __align__(16) short Bs[128 * 32];
  const int tid = threadIdx.x;
  const int lane = tid & 63;
  const int w = tid >> 6;
  const int wr = w >> 1, wc = w & 1;
  const int nwg = gridDim.x * gridDim.y;
  const int lin = blockIdx.y * gridDim.x + blockIdx.x;
  const int tile = (lin & 7) * (nwg >> 3) + (lin >> 3);
  const int row0 = (tile / gridDim.x) * 128;
  const int col0 = (tile % gridDim.x) * 128;
  const int lrow = lane & 15, lkg = lane >> 4;

  f32x4 acc[4][4];
#pragma unroll
  for (int i = 0; i < 4; ++i)
#pragma unroll
    for (int j = 0; j < 4; ++j) acc[i][j] = (f32x4){0.f, 0.f, 0.f, 0.f};

  const short* Ab = A + (size_t)row0 * Kdim;
  const short* Bb = Bt + (size_t)col0 * Kdim;
  const int sr = tid >> 2;
  const int sc = (tid & 3) * 8;

  for (int kt = 0; kt < Kdim; kt += 32) {
    gload16(Ab + (size_t)sr * Kdim + kt + sc, As + tid * 8);
    gload16(Ab + (size_t)(sr + 64) * Kdim + kt + sc, As + 2048 + tid * 8);
    gload16(Bb + (size_t)sr * Kdim + kt + sc, Bs + tid * 8);
    gload16(Bb + (size_t)(sr + 64) * Kdim + kt + sc, Bs + 2048 + tid * 8);
    __syncthreads();
    short8 af[4], bfr[4];
#pragma unroll
    for (int i = 0; i < 4; ++i)
      af[i] = *(const short8*)(As + (wr * 64 + i * 16 + lrow) * 32 + lkg * 8);
#pragma unroll
    for (int j = 0; j < 4; ++j)
      bfr[j] = *(const short8*)(Bs + (wc * 64 + j * 16 + lrow) * 32 + lkg * 8);
#pragma unroll
    for (int i = 0; i < 4; ++i)
#pragma unroll
      for (int j = 0; j < 4; ++j)
        acc[i][j] = __builtin_amdgcn_mfma_f32_16x16x32_bf16(af[i], bfr[j], acc[i][j], 0, 0, 0);
    __syncthreads();
  }

#pragma unroll
  for (int i = 0; i < 4; ++i) {
#pragma unroll
    for (int j = 0; j < 4; ++j) {
      const int gn = col0 + wc * 64 + j * 16 + lrow;
      const int gmb = row0 + wr * 64 + i * 16 + lkg * 4;  // +r<4 never crosses 2048
      float vr[4];
#pragma unroll
      for (int r = 0; r < 4; ++r) vr[r] = acc[i][j][r] + bias[gn];
      if (EPI == 0) {
        const int which = gn >> 10;
        const int hh = (gn >> 6) & 15;
        const int dd = gn & 63;
        const int b = gmb >> 11;
        const int tt0 = gmb & 2047;
        const size_t bh = (size_t)b * NHEADS + hh;
        if (which == 0) {
#pragma unroll
          for (int r = 0; r < 4; ++r)
            q_out[(bh * SEQ + tt0 + r) * HDIM + dd] = f2bf(vr[r] * 0.125f);
        } else if (which == 1) {
#pragma unroll
          for (int r = 0; r < 4; ++r)
            k_out[(bh * SEQ + tt0 + r) * HDIM + (dd ^ (((tt0 + r) & 7) << 3))] = f2bf(vr[r]);
        } else {
          short4v pk;
#pragma unroll
          for (int r = 0; r < 4; ++r) pk[r] = f2bf(vr[r]);
          *(short4v*)(v_out + (bh * HDIM + dd) * SEQ + (tt0 ^ ((dd & 7) << 3))) = pk;
        }
      } else {
#pragma unroll
        for (int r = 0; r < 4; ++r)
          foutp[(size_t)(gmb + r) * Ndim + gn] = vr[r];
      }
    }
  }
}

// gemm2-specialized 64x128 tile (M x N): grid (N/128=8, M/64=128) = 1024 blocks
// = 4 blocks/CU (vs 512 = 2/CU at 128x128, which starved TLP: 207 TF, R13).
// 4 waves each own 32x64 (acc[2][4]); LDS 12KB; same 2-phase staging pattern.
__global__ __launch_bounds__(256, 4) void gemm_n1024_kernel(
    const short* __restrict__ A, const short* __restrict__ Bt,
    const float* __restrict__ bias, float* __restrict__ foutp, int Kdim) {
  __shared__ __align__(16) short As[64 * 32];
  __shared__ __align__(16) short Bs[128 * 32];
  const int tid = threadIdx.x;
  const int lane = tid & 63;
  const int w = tid >> 6;
  const int wr = w >> 1, wc = w & 1;
  const int nwg = gridDim.x * gridDim.y;  // 1024
  const int lin = blockIdx.y * gridDim.x + blockIdx.x;
  const int tile = (lin & 7) * (nwg >> 3) + (lin >> 3);
  const int row0 = (tile / gridDim.x) * 64;
  const int col0 = (tile % gridDim.x) * 128;
  const int lrow = lane & 15, lkg = lane >> 4;

  f32x4 acc[2][4];
#pragma unroll
  for (int i = 0; i < 2; ++i)
#pragma unroll
    for (int j = 0; j < 4; ++j) acc[i][j] = (f32x4){0.f, 0.f, 0.f, 0.f};

  const short* Ab = A + (size_t)row0 * Kdim;
  const short* Bb = Bt + (size_t)col0 * Kdim;
  const int sr = tid >> 2;
  const int sc = (tid & 3) * 8;

  for (int kt = 0; kt < Kdim; kt += 32) {
    gload16(Ab + (size_t)sr * Kdim + kt + sc, As + tid * 8);            // 64 rows
    gload16(Bb + (size_t)sr * Kdim + kt + sc, Bs + tid * 8);            // rows 0-63
    gload16(Bb + (size_t)(sr + 64) * Kdim + kt + sc, Bs + 2048 + tid * 8);  // 64-127
    __syncthreads();
    short8 af[2], bfr[4];
#pragma unroll
    for (int i = 0; i < 2; ++i)
      af[i] = *(const short8*)(As + (wr * 32 + i * 16 + lrow) * 32 + lkg * 8);
#pragma unroll
    for (int j = 0; j < 4; ++j)
      bfr[j] = *(const short8*)(Bs + (wc * 64 + j * 16 + lrow) * 32 + lkg * 8);
#pragma unroll
    for (int i = 0; i < 2; ++i)
#pragma unroll
      for (int j = 0; j < 4; ++j)
        acc[i][j] = __builtin_amdgcn_mfma_f32_16x16x32_bf16(af[i], bfr[j], acc[i][j], 0, 0, 0);
    __syncthreads();
  }

#pragma unroll
  for (int i = 0; i < 2; ++i) {
#pragma unroll
    for (int j = 0; j < 4; ++j) {
      const int gn = col0 + wc * 64 + j * 16 + lrow;
      const int gmb = row0 + wr * 32 + i * 16 + lkg * 4;
#pragma unroll
      for (int r = 0; r < 4; ++r)
        foutp[(size_t)(gmb + r) * DMODEL + gn] = acc[i][j][r] + bias[gn];
    }
  }
}

// One 16-q-row group vs one 64-KV tile: swapped QK^T, in-register softmax
// (tree reductions), exact rescale-skip, permlane P-relayout, PV accumulate.
static __device__ __forceinline__ void attn_rb_tile(
    const short* __restrict__ Ks, const short* __restrict__ Vs,
    const short8 qf[2], f32x4 o[4], float& mr, float& lsum,
    bool diag, int kt, int qq, int lrow, int lkg) {
  f32x4 s[4];
#pragma unroll
  for (int f = 0; f < 4; ++f) s[f] = (f32x4){0.f, 0.f, 0.f, 0.f};

  __builtin_amdgcn_s_setprio(1);
#pragma unroll
  for (int c = 0; c < 2; ++c) {
#pragma unroll
    for (int f = 0; f < 4; ++f) {
      const int krow = f * 16 + lrow;
      const int kel = (c * 32 + lkg * 8) ^ ((krow & 7) << 3);
      short8 kf = *(const short8*)(Ks + krow * 64 + kel);
      s[f] = __builtin_amdgcn_mfma_f32_16x16x32_bf16(kf, qf[c], s[f], 0, 0, 0);
    }
  }
  __builtin_amdgcn_s_setprio(0);

  if (diag) {
#pragma unroll
    for (int f = 0; f < 4; ++f) {
      const int kg = kt + f * 16 + lkg * 4;
#pragma unroll
      for (int r = 0; r < 4; ++r)
        if (kg + r > qq) s[f][r] = -__builtin_inff();
    }
  }

  const float L2E = 1.44269504088896340736f;
  float pm = fmaxf(fmaxf(fmaxf(s[0][0], s[0][1]), fmaxf(s[0][2], s[0][3])),
                   fmaxf(fmaxf(s[1][0], s[1][1]), fmaxf(s[1][2], s[1][3])));
  pm = fmaxf(pm, fmaxf(fmaxf(fmaxf(s[2][0], s[2][1]), fmaxf(s[2][2], s[2][3])),
                       fmaxf(fmaxf(s[3][0], s[3][1]), fmaxf(s[3][2], s[3][3]))));
  pm = fmaxf(pm, __shfl_xor(pm, 16));
  pm = fmaxf(pm, __shfl_xor(pm, 32));
  const float mn = fmaxf(mr, pm);
  if (!__all(pm <= mr)) {
    const float a = fast_exp2((mr - mn) * L2E);
    lsum *= a;
#pragma unroll
    for (int r = 0; r < 4; ++r) {
      const float ar = __shfl(a, lkg * 4 + r, 16);
#pragma unroll
      for (int g = 0; g < 4; ++g) o[g][r] *= ar;
    }
  }
  mr = mn;

  float rf[4];
#pragma unroll
  for (int f = 0; f < 4; ++f) {
#pragma unroll
    for (int r = 0; r < 4; ++r) s[f][r] = fast_exp2((s[f][r] - mn) * L2E);
    rf[f] = (s[f][0] + s[f][1]) + (s[f][2] + s[f][3]);  // tree
  }
  float rs = (rf[0] + rf[1]) + (rf[2] + rf[3]);
  rs += __shfl_xor(rs, 16);
  rs += __shfl_xor(rs, 32);
  lsum += rs;

  unsigned int q32[4][2];
#pragma unroll
  for (int f = 0; f < 4; ++f) {
    q32[f][0] = pack_bf16(s[f][0], s[f][1]);
    q32[f][1] = pack_bf16(s[f][2], s[f][3]);
  }

  __builtin_amdgcn_s_setprio(1);
#pragma unroll
  for (int c = 0; c < 2; ++c) {
    uint4v pw;
#pragma unroll
    for (int h = 0; h < 2; ++h) {
      unsigned int a = q32[2 * c][h], b = q32[2 * c + 1][h];
      permlane32_swap(a, b);
      permlane16_swap(a, b);
      pw[h] = a; pw[2 + h] = b;
    }
    const short8 pf = __builtin_bit_cast(short8, pw);
#pragma unroll
    for (int g = 0; g < 4; ++g) {
      const int vrow = g * 16 + lrow;
      const int vel = (c * 32 + lkg * 8) ^ ((vrow & 7) << 3);
      short8 vf = *(const short8*)(Vs + vrow * 64 + vel);
      o[g] = __builtin_amdgcn_mfma_f32_16x16x32_bf16(pf, vf, o[g], 0, 0, 0);
    }
  }
  __builtin_amdgcn_s_setprio(0);
}

// causal flash attention, ROW-SPLIT paired q-tiles (R13-verified): every wave
// owns 16 heavy rows (tile 31-ip) + 16 light rows (tile ip); rb1 active for
// it<=ip (block-uniform) -> zero wave idling, constant block cost.
__global__ __launch_bounds__(256, 4) void attn_kernel(
    const short* __restrict__ qb, const short* __restrict__ kb,
    const short* __restrict__ vb, short* __restrict__ aout) {
  __shared__ __align__(16) short Ks2[2][64 * 64];
  __shared__ __align__(16) short Vs2[2][64 * 64];
  const int tid = threadIdx.x;   // 0..255
  const int lane = tid & 63;
  const int w = tid >> 6;        // 0..3
  const int lin = blockIdx.y * gridDim.x + blockIdx.x;
  const int tile = ((lin & 7) << 7) + (lin >> 3);
  const int bh = tile >> 4;
  const int ip = tile & 15;
  const int heavy_q0 = (31 - ip) * 64;
  const int light_q0 = ip * 64;
  const int qr0 = heavy_q0 + w * 16;
  const int qr1 = light_q0 + w * 16;
  const int lrow = lane & 15, lkg = lane >> 4;

  const short* kbase = kb + (size_t)bh * SEQ * HDIM;
  const short* vbase = vb + (size_t)bh * HDIM * SEQ;

  short8 qf0[2], qf1[2];
  {
    const short* qrow = qb + ((size_t)bh * SEQ + qr0 + lrow) * HDIM;
    qf0[0] = *(const short8*)(qrow + lkg * 8);
    qf0[1] = *(const short8*)(qrow + 32 + lkg * 8);
    const short* qrow1 = qb + ((size_t)bh * SEQ + qr1 + lrow) * HDIM;
    qf1[0] = *(const short8*)(qrow1 + lkg * 8);
    qf1[1] = *(const short8*)(qrow1 + 32 + lkg * 8);
  }

  f32x4 o0[4], o1[4];
  float mr0 = -__builtin_inff(), mr1 = -__builtin_inff();
  float ls0 = 0.f, ls1 = 0.f;
#pragma unroll
  for (int g = 0; g < 4; ++g) {
    o0[g] = (f32x4){0.f, 0.f, 0.f, 0.f};
    o1[g] = (f32x4){0.f, 0.f, 0.f, 0.f};
  }

  const int ntile = 32 - ip;

  {  // prologue: stage tile 0 -> buf 0
    short* Kd = Ks2[0]; short* Vd = Vs2[0];
#pragma unroll
    for (int i = 0; i < 2; ++i)
      gload16(kbase + i * 2048 + tid * 8, Kd + i * 2048 + tid * 8);
#pragma unroll
    for (int i = 0; i < 2; ++i)
      gload16(vbase + (size_t)(32 * i + (tid >> 3)) * SEQ + (tid & 7) * 8,
              Vd + i * 2048 + tid * 8);
  }
  __syncthreads();

  int cur = 0;
  for (int it = 0; it < ntile; ++it) {
    const int kt = it * 64;
    if (it + 1 < ntile) {
      const int k2 = kt + 64;
      short* Kd = Ks2[cur ^ 1]; short* Vd = Vs2[cur ^ 1];
#pragma unroll
      for (int i = 0; i < 2; ++i)
        gload16(kbase + (size_t)k2 * HDIM + i * 2048 + tid * 8, Kd + i * 2048 + tid * 8);
#pragma unroll
      for (int i = 0; i < 2; ++i)
        gload16(vbase + (size_t)(32 * i + (tid >> 3)) * SEQ + k2 + (tid & 7) * 8,
                Vd + i * 2048 + tid * 8);
    }
    const short* Ks = Ks2[cur];
    const short* Vs = Vs2[cur];
    attn_rb_tile(Ks, Vs, qf0, o0, mr0, ls0,
                 kt + 63 > qr0, kt, qr0 + lrow, lrow, lkg);
    if (it <= ip)
      attn_rb_tile(Ks, Vs, qf1, o1, mr1, ls1,
                   kt + 63 > qr1, kt, qr1 + lrow, lrow, lkg);
    __syncthreads();
    cur ^= 1;
  }

  const int b = bh >> 4, h = bh & 15;
  const float li0 = 1.0f / ls0;
  const float li1 = 1.0f / ls1;
#pragma unroll
  for (int r = 0; r < 4; ++r) {
    const float i0 = __shfl(li0, lkg * 4 + r, 16);
    const float i1 = __shfl(li1, lkg * 4 + r, 16);
    const int t0 = qr0 + lkg * 4 + r;
    const int t1 = qr1 + lkg * 4 + r;
#pragma unroll
    for (int g = 0; g < 4; ++g) {
      aout[((size_t)b * SEQ + t0) * DMODEL + h * 64 + g * 16 + lrow] = f2bf(o0[g][r] * i0);
      aout[((size_t)b * SEQ + t1) * DMODEL + h * 64 + g * 16 + lrow] = f2bf(o1[g][r] * i1);
    }
  }
}

extern "C" void kernel_launch(void* const* d_in, const int* in_sizes, int n_in,
                              void* d_out, int out_size, void* d_ws, size_t ws_size,
                              hipStream_t stream) {
  const float* x = (const float*)d_in[0];
  // d_in[1] = mask (causal tril) — hardcoded in attn kernel
  const float* Wqkv = (const float*)d_in[2];
  const float* bqkv = (const float*)d_in[3];
  const float* Wout = (const float*)d_in[4];
  const float* bout = (const float*)d_in[5];

  char* ws = (char*)d_ws;
  short* xb    = (short*)(ws + 0);         // 16,777,216 B
  short* wqkvT = (short*)(ws + 16777216);  //  6,291,456 B
  short* woutT = (short*)(ws + 23068672);  //  2,097,152 B
  short* qbuf  = (short*)(ws + 25165824);  // 16,777,216 B
  short* kbuf  = (short*)(ws + 41943040);  // 16,777,216 B (row-swizzled)
  short* vbuf  = (short*)(ws + 58720256);  // 16,777,216 B (V^T per head, swizzled)
  short* abuf  = (short*)(ws + 75497472);  // 16,777,216 B — total 92,274,688 B

  cast_x_kernel<<<(MROWS * DMODEL) / 4 / 256, 256, 0, stream>>>(x, xb, MROWS * DMODEL);
  transpose_cast_kernel<<<dim3(N3 / 32, DMODEL / 32), dim3(32, 8), 0, stream>>>(
      Wqkv, wqkvT, DMODEL, N3);
  transpose_cast_kernel<<<dim3(DMODEL / 32, DMODEL / 32), dim3(32, 8), 0, stream>>>(
      Wout, woutT, DMODEL, DMODEL);
  gemm128_kernel<0><<<dim3(N3 / 128, MROWS / 128), 256, 0, stream>>>(
      xb, wqkvT, bqkv, nullptr, qbuf, kbuf, vbuf, MROWS, N3, DMODEL);
  attn_kernel<<<dim3(16, BHCNT), 256, 0, stream>>>(qbuf, kbuf, vbuf, abuf);
  gemm_n1024_kernel<<<dim3(DMODEL / 128, MROWS / 64), 256, 0, stream>>>(
      abuf, woutT, bout, (float*)d_out, DMODEL);
}